// Round 2
// baseline (4540.829 us; speedup 1.0000x reference)
//
#include <hip/hip_runtime.h>

// GraphSAGE 2-layer forward, MI355X.
// N=100000 nodes, E=1600000 edges, F=128, H=128, OUT=64. All f32.
// Layout of d_ws (floats):
//   agg1/h : N*128   (aggregate sum for layer1; overwritten in-place with h)
//   tr     : N*128   (cols 0..63 = h@W2l.T, cols 64..127 = h@W2r.T)
//   cnt    : N
//   W1lT   : 128*128 (transposed [k][j])
//   W1rT   : 128*128
//   W2T    : 128*128 (combined transposed: j<64 -> W2l, j>=64 -> W2r)

#define NN 100000
#define NE 1600000

// ---- weight prep: transpose to [k][j] for coalesced GEMM loads ----
__global__ void prep_w_k(const float* __restrict__ W1l, const float* __restrict__ W1r,
                         const float* __restrict__ W2l, const float* __restrict__ W2r,
                         float* __restrict__ W1lT, float* __restrict__ W1rT,
                         float* __restrict__ W2T) {
    int t = blockIdx.x * 256 + threadIdx.x;   // 0..16383
    int k = t >> 7, j = t & 127;
    W1lT[t] = W1l[j * 128 + k];
    W1rT[t] = W1r[j * 128 + k];
    W2T[t]  = (j < 64) ? W2l[j * 128 + k] : W2r[(j - 64) * 128 + k];
}

// ---- degree count ----
__global__ void degree_k(const int* __restrict__ dst, float* __restrict__ cnt) {
    int i = blockIdx.x * 256 + threadIdx.x;   // grid exact: NE/256
    atomicAdd(&cnt[dst[i]], 1.0f);
}

// ---- layer1 scatter: agg1[dst] += x[src], 128-wide, 32 threads/edge ----
__global__ void scatter128_k(const float* __restrict__ x, const int* __restrict__ src,
                             const int* __restrict__ dst, float* __restrict__ agg) {
    int gid = blockIdx.x * 256 + threadIdx.x; // grid exact: NE*32/256
    int e = gid >> 5;
    int c = (gid & 31) << 2;
    int s = src[e], d = dst[e];
    float4 v = *(const float4*)(x + (size_t)s * 128 + c);
    float* p = agg + (size_t)d * 128 + c;
    atomicAdd(p + 0, v.x);
    atomicAdd(p + 1, v.y);
    atomicAdd(p + 2, v.z);
    atomicAdd(p + 3, v.w);
}

// ---- layer1 node update: h = relu(normalize(mean@W1l.T + b1l + x@W1r.T)) ----
// 32 nodes/block, 256 threads. In-place: reads agg row into LDS, writes h back.
__global__ __launch_bounds__(256) void l1_node_k(
    float* __restrict__ agg_h, const float* __restrict__ x,
    const float* __restrict__ cnt, const float* __restrict__ W1lT,
    const float* __restrict__ W1rT, const float* __restrict__ b1l) {
    __shared__ float ms[32][128];
    __shared__ float xs[32][128];
    __shared__ float outs[32][128];
    __shared__ float scale_s[32];
    const int t = threadIdx.x;
    const size_t base = (size_t)blockIdx.x * 32;

    for (int i = 0; i < 4; ++i) {            // 1024 float4 per array
        int idx = i * 256 + t;
        int n = idx >> 5, c = idx & 31;
        ((float4*)&ms[n][0])[c] = ((const float4*)(agg_h + (base + n) * 128))[c];
        ((float4*)&xs[n][0])[c] = ((const float4*)(x + (base + n) * 128))[c];
    }
    if (t < 32) scale_s[t] = 1.0f / fmaxf(cnt[base + t], 1.0f);
    __syncthreads();
    for (int i = 0; i < 16; ++i) {           // ms *= 1/max(cnt,1)
        int idx = i * 256 + t;
        int n = idx >> 7, c = idx & 127;
        ms[n][c] *= scale_s[n];
    }
    __syncthreads();

    const int j = t & 127;
    const int ng = (t >> 7) * 16;
    float acc[16];
#pragma unroll
    for (int i = 0; i < 16; ++i) acc[i] = 0.0f;
    for (int k = 0; k < 128; ++k) {
        float a = W1lT[k * 128 + j];         // lane-coalesced (j = lane)
        float b = W1rT[k * 128 + j];
#pragma unroll
        for (int i = 0; i < 16; ++i)
            acc[i] += ms[ng + i][k] * a + xs[ng + i][k] * b;   // LDS broadcast
    }
    float bias = b1l[j];
#pragma unroll
    for (int i = 0; i < 16; ++i) outs[ng + i][j] = acc[i] + bias;
    __syncthreads();
    {
        int n = t >> 3, lo = (t & 7) * 16;   // 8 lanes per node
        float s = 0.0f;
#pragma unroll
        for (int i = 0; i < 16; ++i) { float v = outs[n][lo + i]; s += v * v; }
        s += __shfl_xor(s, 1);
        s += __shfl_xor(s, 2);
        s += __shfl_xor(s, 4);
        if ((t & 7) == 0) scale_s[n] = 1.0f / fmaxf(sqrtf(s), 1e-12f);
    }
    __syncthreads();
    for (int i = 0; i < 16; ++i) {
        int idx = i * 256 + t;
        int n = idx >> 7, c = idx & 127;
        agg_h[(base + n) * 128 + c] = fmaxf(outs[n][c] * scale_s[n], 0.0f);
    }
}

// ---- layer2 transform: tr[n][0:64]=h@W2l.T, tr[n][64:128]=h@W2r.T ----
__global__ __launch_bounds__(256) void l2_transform_k(
    const float* __restrict__ h, const float* __restrict__ W2T,
    float* __restrict__ tr) {
    __shared__ float hs[32][128];
    const int t = threadIdx.x;
    const size_t base = (size_t)blockIdx.x * 32;
    for (int i = 0; i < 4; ++i) {
        int idx = i * 256 + t;
        int n = idx >> 5, c = idx & 31;
        ((float4*)&hs[n][0])[c] = ((const float4*)(h + (base + n) * 128))[c];
    }
    __syncthreads();
    const int j = t & 127;
    const int ng = (t >> 7) * 16;
    float acc[16];
#pragma unroll
    for (int i = 0; i < 16; ++i) acc[i] = 0.0f;
    for (int k = 0; k < 128; ++k) {
        float a = W2T[k * 128 + j];
#pragma unroll
        for (int i = 0; i < 16; ++i) acc[i] += hs[ng + i][k] * a;
    }
#pragma unroll
    for (int i = 0; i < 16; ++i) tr[(base + ng + i) * 128 + j] = acc[i];
}

// ---- layer2 scatter: agg2[dst] += t[src] (64-wide), 16 threads/edge ----
__global__ void scatter64_k(const float* __restrict__ tr, const int* __restrict__ src,
                            const int* __restrict__ dst, float* __restrict__ agg2) {
    int gid = blockIdx.x * 256 + threadIdx.x; // grid exact: NE*16/256
    int e = gid >> 4;
    int c = (gid & 15) << 2;
    int s = src[e], d = dst[e];
    float4 v = *(const float4*)(tr + (size_t)s * 128 + c);   // cols 0..63 = t
    float* p = agg2 + (size_t)d * 64 + c;
    atomicAdd(p + 0, v.x);
    atomicAdd(p + 1, v.y);
    atomicAdd(p + 2, v.z);
    atomicAdd(p + 3, v.w);
}

// ---- final: out = normalize(agg2/cnt + b2l + r), one wave per node ----
__global__ __launch_bounds__(256) void l2_final_k(
    float* __restrict__ out, const float* __restrict__ cnt,
    const float* __restrict__ b2l, const float* __restrict__ tr) {
    const int t = threadIdx.x;
    const size_t n = (size_t)blockIdx.x * 4 + (t >> 6);
    const int c = t & 63;
    float inv = 1.0f / fmaxf(cnt[n], 1.0f);
    float v = out[n * 64 + c] * inv + b2l[c] + tr[n * 128 + 64 + c];
    float s = v * v;
    for (int o = 1; o < 64; o <<= 1) s += __shfl_xor(s, o);
    float scale = 1.0f / fmaxf(sqrtf(s), 1e-12f);
    out[n * 64 + c] = v * scale;
}

extern "C" void kernel_launch(void* const* d_in, const int* in_sizes, int n_in,
                              void* d_out, int out_size, void* d_ws, size_t ws_size,
                              hipStream_t stream) {
    const float* x   = (const float*)d_in[0];
    const int*   ei  = (const int*)d_in[1];
    const float* W1l = (const float*)d_in[2];
    const float* b1l = (const float*)d_in[3];
    const float* W1r = (const float*)d_in[4];
    const float* W2l = (const float*)d_in[5];
    const float* b2l = (const float*)d_in[6];
    const float* W2r = (const float*)d_in[7];
    const int* src = ei;
    const int* dst = ei + NE;
    float* out = (float*)d_out;

    float* agg1 = (float*)d_ws;                         // N*128, becomes h
    float* tr   = agg1 + (size_t)NN * 128;              // N*128
    float* cnt  = tr + (size_t)NN * 128;                // N
    float* W1lT = cnt + NN;                             // 128*128
    float* W1rT = W1lT + 128 * 128;
    float* W2T  = W1rT + 128 * 128;

    hipMemsetAsync(agg1, 0, (size_t)NN * 128 * sizeof(float), stream);
    hipMemsetAsync(cnt, 0, (size_t)NN * sizeof(float), stream);
    hipMemsetAsync(out, 0, (size_t)NN * 64 * sizeof(float), stream);  // agg2 accumulator

    prep_w_k<<<64, 256, 0, stream>>>(W1l, W1r, W2l, W2r, W1lT, W1rT, W2T);
    degree_k<<<NE / 256, 256, 0, stream>>>(dst, cnt);
    scatter128_k<<<NE * 32 / 256, 256, 0, stream>>>(x, src, dst, agg1);
    l1_node_k<<<NN / 32, 256, 0, stream>>>(agg1, x, cnt, W1lT, W1rT, b1l);
    l2_transform_k<<<NN / 32, 256, 0, stream>>>(agg1, W2T, tr);
    scatter64_k<<<NE * 16 / 256, 256, 0, stream>>>(tr, src, dst, out);
    l2_final_k<<<NN / 4, 256, 0, stream>>>(out, cnt, b2l, tr);
}

// Round 3
// 803.103 us; speedup vs baseline: 5.6541x; 5.6541x over previous
//
#include <hip/hip_runtime.h>

// GraphSAGE 2-layer forward, MI355X — CSR gather version (no f32 atomics).
// N=100000, E=1600000, F=128, H=128, OUT=64. All f32.
//
// d_ws layout (floats):
//   A     : N*128  (mean -> h -> tr, reused in place)
//   esrc  : NE     (int: src ids bucketed by dst)
//   start : N+1    (int: CSR row starts)
//   cnt   : N      (int: degree histogram)
//   fill  : N      (int: bucket fill cursors)
//   btot  : 128    (int: scan block totals)
//   W1lT, W1rT, W2T : 128*128 each (transposed weights)

#define NN 100000
#define NE 1600000
#define SCAN_B 1024
#define NB_SCAN ((NN + SCAN_B - 1) / SCAN_B)   // 98

// ---- weight prep: transpose to [k][j] for coalesced GEMM loads ----
__global__ void prep_w_k(const float* __restrict__ W1l, const float* __restrict__ W1r,
                         const float* __restrict__ W2l, const float* __restrict__ W2r,
                         float* __restrict__ W1lT, float* __restrict__ W1rT,
                         float* __restrict__ W2T) {
    int t = blockIdx.x * 256 + threadIdx.x;   // 0..16383
    int k = t >> 7, j = t & 127;
    W1lT[t] = W1l[j * 128 + k];
    W1rT[t] = W1r[j * 128 + k];
    W2T[t]  = (j < 64) ? W2l[j * 128 + k] : W2r[(j - 64) * 128 + k];
}

// ---- degree histogram (int atomics, 1.6M ops) ----
__global__ void hist_k(const int* __restrict__ dst, int* __restrict__ cnt) {
    int e = blockIdx.x * 256 + threadIdx.x;   // grid exact NE/256
    atomicAdd(&cnt[dst[e]], 1);
}

// ---- exclusive scan pass 1: per-block (1024 elems, 256 thr x 4) ----
__global__ void scan1_k(const int* __restrict__ cnt, int* __restrict__ start,
                        int* __restrict__ btot) {
    __shared__ int sd[256];
    int b = blockIdx.x, t = threadIdx.x;
    int base = b * SCAN_B + t * 4;
    int v0 = (base + 0 < NN) ? cnt[base + 0] : 0;
    int v1 = (base + 1 < NN) ? cnt[base + 1] : 0;
    int v2 = (base + 2 < NN) ? cnt[base + 2] : 0;
    int v3 = (base + 3 < NN) ? cnt[base + 3] : 0;
    int sum = v0 + v1 + v2 + v3;
    sd[t] = sum;
    __syncthreads();
    for (int o = 1; o < 256; o <<= 1) {
        int x = (t >= o) ? sd[t - o] : 0;
        __syncthreads();
        sd[t] += x;
        __syncthreads();
    }
    int run = sd[t] - sum;                    // exclusive prefix of this chunk
    if (base + 0 < NN) start[base + 0] = run; run += v0;
    if (base + 1 < NN) start[base + 1] = run; run += v1;
    if (base + 2 < NN) start[base + 2] = run; run += v2;
    if (base + 3 < NN) start[base + 3] = run;
    if (t == 255) btot[b] = sd[255];
}

// ---- scan pass 2: exclusive scan of 98 block totals (1 block) ----
__global__ void scan2_k(int* __restrict__ btot) {
    __shared__ int sd[128];
    int t = threadIdx.x;
    int v = (t < NB_SCAN) ? btot[t] : 0;
    sd[t] = v;
    __syncthreads();
    for (int o = 1; o < 128; o <<= 1) {
        int x = (t >= o) ? sd[t - o] : 0;
        __syncthreads();
        sd[t] += x;
        __syncthreads();
    }
    if (t < NB_SCAN) btot[t] = sd[t] - v;
}

// ---- scan pass 3: add block offsets; set start[NN]=NE ----
__global__ void scan3_k(int* __restrict__ start, const int* __restrict__ btot) {
    int b = blockIdx.x;
    int off = btot[b];
    int base = b * SCAN_B + threadIdx.x;
#pragma unroll
    for (int i = 0; i < 4; ++i) {
        int idx = base + i * 256;
        if (idx < NN) start[idx] += off;
    }
    if (b == 0 && threadIdx.x == 0) start[NN] = NE;
}

// ---- bucket fill: esrc[start[d] + cursor] = src[e] ----
__global__ void fill_k(const int* __restrict__ src, const int* __restrict__ dst,
                       const int* __restrict__ start, int* __restrict__ fill,
                       int* __restrict__ esrc) {
    int e = blockIdx.x * 256 + threadIdx.x;   // grid exact NE/256
    int d = dst[e];
    int pos = start[d] + atomicAdd(&fill[d], 1);
    esrc[pos] = src[e];
}

// ---- layer1 gather-aggregate: A[n] = mean over edges of x[src], one wave/node ----
__global__ __launch_bounds__(256) void agg1_k(const float* __restrict__ x,
                                              const int* __restrict__ esrc,
                                              const int* __restrict__ start,
                                              float* __restrict__ A) {
    int n = blockIdx.x * 4 + (threadIdx.x >> 6);   // grid exact NN/4
    int lane = threadIdx.x & 63;
    int s0 = start[n], s1 = start[n + 1];
    float2 a0 = {0.f, 0.f}, a1 = {0.f, 0.f};
    int e = s0;
    for (; e + 1 < s1; e += 2) {                   // 2 independent chains
        int sa = esrc[e], sb = esrc[e + 1];
        float2 va = *(const float2*)(x + (size_t)sa * 128 + lane * 2);
        float2 vb = *(const float2*)(x + (size_t)sb * 128 + lane * 2);
        a0.x += va.x; a0.y += va.y;
        a1.x += vb.x; a1.y += vb.y;
    }
    if (e < s1) {
        int sa = esrc[e];
        float2 va = *(const float2*)(x + (size_t)sa * 128 + lane * 2);
        a0.x += va.x; a0.y += va.y;
    }
    float inv = 1.0f / fmaxf((float)(s1 - s0), 1.0f);
    float2 r = {(a0.x + a1.x) * inv, (a0.y + a1.y) * inv};
    *(float2*)(A + (size_t)n * 128 + lane * 2) = r;
}

// ---- layer1 node update: h = relu(normalize(mean@W1l.T + b1l + x@W1r.T)) ----
// 32 nodes/block; reads mean rows from A, writes h rows back in place.
__global__ __launch_bounds__(256) void l1_node_k(
    float* __restrict__ A, const float* __restrict__ x,
    const float* __restrict__ W1lT, const float* __restrict__ W1rT,
    const float* __restrict__ b1l) {
    __shared__ float ms[32][128];
    __shared__ float xs[32][128];
    __shared__ float outs[32][128];
    __shared__ float scale_s[32];
    const int t = threadIdx.x;
    const size_t base = (size_t)blockIdx.x * 32;

    for (int i = 0; i < 4; ++i) {
        int idx = i * 256 + t;
        int n = idx >> 5, c = idx & 31;
        ((float4*)&ms[n][0])[c] = ((const float4*)(A + (base + n) * 128))[c];
        ((float4*)&xs[n][0])[c] = ((const float4*)(x + (base + n) * 128))[c];
    }
    __syncthreads();

    const int j = t & 127;
    const int ng = (t >> 7) * 16;
    float acc[16];
#pragma unroll
    for (int i = 0; i < 16; ++i) acc[i] = 0.0f;
    for (int k = 0; k < 128; ++k) {
        float a = W1lT[k * 128 + j];
        float b = W1rT[k * 128 + j];
#pragma unroll
        for (int i = 0; i < 16; ++i)
            acc[i] += ms[ng + i][k] * a + xs[ng + i][k] * b;
    }
    float bias = b1l[j];
#pragma unroll
    for (int i = 0; i < 16; ++i) outs[ng + i][j] = acc[i] + bias;
    __syncthreads();
    {
        int n = t >> 3, lo = (t & 7) * 16;
        float s = 0.0f;
#pragma unroll
        for (int i = 0; i < 16; ++i) { float v = outs[n][lo + i]; s += v * v; }
        s += __shfl_xor(s, 1);
        s += __shfl_xor(s, 2);
        s += __shfl_xor(s, 4);
        if ((t & 7) == 0) scale_s[n] = 1.0f / fmaxf(sqrtf(s), 1e-12f);
    }
    __syncthreads();
    for (int i = 0; i < 16; ++i) {
        int idx = i * 256 + t;
        int n = idx >> 7, c = idx & 127;
        A[(base + n) * 128 + c] = fmaxf(outs[n][c] * scale_s[n], 0.0f);
    }
}

// ---- layer2 transform (in place): A[n][0:64]=h@W2l.T, A[n][64:128]=h@W2r.T ----
__global__ __launch_bounds__(256) void l2_transform_k(
    float* __restrict__ A, const float* __restrict__ W2T) {
    __shared__ float hs[32][128];
    const int t = threadIdx.x;
    const size_t base = (size_t)blockIdx.x * 32;
    for (int i = 0; i < 4; ++i) {
        int idx = i * 256 + t;
        int n = idx >> 5, c = idx & 31;
        ((float4*)&hs[n][0])[c] = ((const float4*)(A + (base + n) * 128))[c];
    }
    __syncthreads();
    const int j = t & 127;
    const int ng = (t >> 7) * 16;
    float acc[16];
#pragma unroll
    for (int i = 0; i < 16; ++i) acc[i] = 0.0f;
    for (int k = 0; k < 128; ++k) {
        float a = W2T[k * 128 + j];
#pragma unroll
        for (int i = 0; i < 16; ++i) acc[i] += hs[ng + i][k] * a;
    }
#pragma unroll
    for (int i = 0; i < 16; ++i) A[(base + ng + i) * 128 + j] = acc[i];
}

// ---- layer2 gather + bias + self + normalize, one wave/node ----
__global__ __launch_bounds__(256) void l2_final_k(
    const float* __restrict__ A, const int* __restrict__ esrc,
    const int* __restrict__ start, const float* __restrict__ b2l,
    float* __restrict__ out) {
    int n = blockIdx.x * 4 + (threadIdx.x >> 6);   // grid exact NN/4
    int c = threadIdx.x & 63;
    int s0 = start[n], s1 = start[n + 1];
    float a0 = 0.f, a1 = 0.f;
    int e = s0;
    for (; e + 1 < s1; e += 2) {
        a0 += A[(size_t)esrc[e] * 128 + c];
        a1 += A[(size_t)esrc[e + 1] * 128 + c];
    }
    if (e < s1) a0 += A[(size_t)esrc[e] * 128 + c];
    float inv = 1.0f / fmaxf((float)(s1 - s0), 1.0f);
    float v = (a0 + a1) * inv + b2l[c] + A[(size_t)n * 128 + 64 + c];
    float s = v * v;
    for (int o = 1; o < 64; o <<= 1) s += __shfl_xor(s, o);
    out[(size_t)n * 64 + c] = v / fmaxf(sqrtf(s), 1e-12f);
}

extern "C" void kernel_launch(void* const* d_in, const int* in_sizes, int n_in,
                              void* d_out, int out_size, void* d_ws, size_t ws_size,
                              hipStream_t stream) {
    const float* x   = (const float*)d_in[0];
    const int*   ei  = (const int*)d_in[1];
    const float* W1l = (const float*)d_in[2];
    const float* b1l = (const float*)d_in[3];
    const float* W1r = (const float*)d_in[4];
    const float* W2l = (const float*)d_in[5];
    const float* b2l = (const float*)d_in[6];
    const float* W2r = (const float*)d_in[7];
    const int* src = ei;
    const int* dst = ei + NE;
    float* out = (float*)d_out;

    float* A    = (float*)d_ws;                         // N*128
    int*   esrc = (int*)(A + (size_t)NN * 128);         // NE
    int*   start = esrc + NE;                           // N+1
    int*   cnt  = start + NN + 1;                       // N
    int*   fill = cnt + NN;                             // N
    int*   btot = fill + NN;                            // 128
    float* W1lT = (float*)(btot + 128);                 // 128*128
    float* W1rT = W1lT + 128 * 128;
    float* W2T  = W1rT + 128 * 128;

    hipMemsetAsync(cnt, 0, (size_t)NN * sizeof(int), stream);
    hipMemsetAsync(fill, 0, (size_t)NN * sizeof(int), stream);

    prep_w_k<<<64, 256, 0, stream>>>(W1l, W1r, W2l, W2r, W1lT, W1rT, W2T);
    hist_k<<<NE / 256, 256, 0, stream>>>(dst, cnt);
    scan1_k<<<NB_SCAN, 256, 0, stream>>>(cnt, start, btot);
    scan2_k<<<1, 128, 0, stream>>>(btot);
    scan3_k<<<NB_SCAN, 256, 0, stream>>>(start, btot);
    fill_k<<<NE / 256, 256, 0, stream>>>(src, dst, start, fill, esrc);
    agg1_k<<<NN / 4, 256, 0, stream>>>(x, esrc, start, A);
    l1_node_k<<<NN / 32, 256, 0, stream>>>(A, x, W1lT, W1rT, b1l);
    l2_transform_k<<<NN / 32, 256, 0, stream>>>(A, W2T);
    l2_final_k<<<NN / 4, 256, 0, stream>>>(A, esrc, start, b2l, out);
}

// Round 4
// 763.926 us; speedup vs baseline: 5.9441x; 1.0513x over previous
//
#include <hip/hip_runtime.h>

// GraphSAGE 2-layer forward, MI355X — CSR gather + fused node GEMMs.
// N=100000, E=1600000, F=128, H=128, OUT=64. All f32.
//
// d_ws layout:
//   A     : N*128 f32  (mean -> tr, in place per block)
//   esrc  : NE   int   (src ids bucketed by dst)
//   start : N+1  int   (CSR row starts)
//   cnt   : N    int
//   fill  : N    int
//   btot  : 128  int
//   W1lT, W1rT, W2T : 128*128 f32 (transposed [k][j])

#define NN 100000
#define NE 1600000
#define SCAN_B 1024
#define NB_SCAN ((NN + SCAN_B - 1) / SCAN_B)   // 98

// ---- weight prep: transpose to [k][j] for coalesced GEMM loads ----
__global__ void prep_w_k(const float* __restrict__ W1l, const float* __restrict__ W1r,
                         const float* __restrict__ W2l, const float* __restrict__ W2r,
                         float* __restrict__ W1lT, float* __restrict__ W1rT,
                         float* __restrict__ W2T) {
    int t = blockIdx.x * 256 + threadIdx.x;   // 0..16383
    int k = t >> 7, j = t & 127;
    W1lT[t] = W1l[j * 128 + k];
    W1rT[t] = W1r[j * 128 + k];
    W2T[t]  = (j < 64) ? W2l[j * 128 + k] : W2r[(j - 64) * 128 + k];
}

// ---- degree histogram ----
__global__ void hist_k(const int* __restrict__ dst, int* __restrict__ cnt) {
    int e = blockIdx.x * 256 + threadIdx.x;   // grid exact NE/256
    atomicAdd(&cnt[dst[e]], 1);
}

// ---- exclusive scan pass 1 ----
__global__ void scan1_k(const int* __restrict__ cnt, int* __restrict__ start,
                        int* __restrict__ btot) {
    __shared__ int sd[256];
    int b = blockIdx.x, t = threadIdx.x;
    int base = b * SCAN_B + t * 4;
    int v0 = (base + 0 < NN) ? cnt[base + 0] : 0;
    int v1 = (base + 1 < NN) ? cnt[base + 1] : 0;
    int v2 = (base + 2 < NN) ? cnt[base + 2] : 0;
    int v3 = (base + 3 < NN) ? cnt[base + 3] : 0;
    int sum = v0 + v1 + v2 + v3;
    sd[t] = sum;
    __syncthreads();
    for (int o = 1; o < 256; o <<= 1) {
        int x = (t >= o) ? sd[t - o] : 0;
        __syncthreads();
        sd[t] += x;
        __syncthreads();
    }
    int run = sd[t] - sum;
    if (base + 0 < NN) start[base + 0] = run; run += v0;
    if (base + 1 < NN) start[base + 1] = run; run += v1;
    if (base + 2 < NN) start[base + 2] = run; run += v2;
    if (base + 3 < NN) start[base + 3] = run;
    if (t == 255) btot[b] = sd[255];
}

// ---- scan pass 2 ----
__global__ void scan2_k(int* __restrict__ btot) {
    __shared__ int sd[128];
    int t = threadIdx.x;
    int v = (t < NB_SCAN) ? btot[t] : 0;
    sd[t] = v;
    __syncthreads();
    for (int o = 1; o < 128; o <<= 1) {
        int x = (t >= o) ? sd[t - o] : 0;
        __syncthreads();
        sd[t] += x;
        __syncthreads();
    }
    if (t < NB_SCAN) btot[t] = sd[t] - v;
}

// ---- scan pass 3 ----
__global__ void scan3_k(int* __restrict__ start, const int* __restrict__ btot) {
    int b = blockIdx.x;
    int off = btot[b];
    int base = b * SCAN_B + threadIdx.x;
#pragma unroll
    for (int i = 0; i < 4; ++i) {
        int idx = base + i * 256;
        if (idx < NN) start[idx] += off;
    }
    if (b == 0 && threadIdx.x == 0) start[NN] = NE;
}

// ---- bucket fill ----
__global__ void fill_k(const int* __restrict__ src, const int* __restrict__ dst,
                       const int* __restrict__ start, int* __restrict__ fill,
                       int* __restrict__ esrc) {
    int e = blockIdx.x * 256 + threadIdx.x;   // grid exact NE/256
    int d = dst[e];
    int pos = start[d] + atomicAdd(&fill[d], 1);
    esrc[pos] = src[e];
}

// ---- layer1 gather-aggregate: A[n] = mean of x[src] over edges, 1 wave/node ----
__global__ __launch_bounds__(256) void agg1_k(const float* __restrict__ x,
                                              const int* __restrict__ esrc,
                                              const int* __restrict__ start,
                                              float* __restrict__ A) {
    int n = blockIdx.x * 4 + (threadIdx.x >> 6);   // grid exact NN/4
    int lane = threadIdx.x & 63;
    int s0 = start[n], s1 = start[n + 1];
    float2 a0 = {0.f, 0.f}, a1 = {0.f, 0.f};
    int e = s0;
    for (; e + 1 < s1; e += 2) {
        int sa = esrc[e], sb = esrc[e + 1];
        float2 va = *(const float2*)(x + (size_t)sa * 128 + lane * 2);
        float2 vb = *(const float2*)(x + (size_t)sb * 128 + lane * 2);
        a0.x += va.x; a0.y += va.y;
        a1.x += vb.x; a1.y += vb.y;
    }
    if (e < s1) {
        int sa = esrc[e];
        float2 va = *(const float2*)(x + (size_t)sa * 128 + lane * 2);
        a0.x += va.x; a0.y += va.y;
    }
    float inv = 1.0f / fmaxf((float)(s1 - s0), 1.0f);
    float2 r = {(a0.x + a1.x) * inv, (a0.y + a1.y) * inv};
    *(float2*)(A + (size_t)n * 128 + lane * 2) = r;
}

// ---- fused node kernel: h = relu(norm(mean@W1l.T + b1l + x@W1r.T));
//      A <- [h@W2l.T | h@W2r.T]   (32 nodes/block, 256 threads)
__global__ __launch_bounds__(256) void l12_node_k(
    float* __restrict__ A, const float* __restrict__ x,
    const float* __restrict__ W1lT, const float* __restrict__ W1rT,
    const float* __restrict__ W2T, const float* __restrict__ b1l) {
    __shared__ __align__(16) float ms[32][128];   // mean -> h
    __shared__ __align__(16) float xs[32][128];   // x    -> pre-norm out
    __shared__ float scale_s[32];
    const int t = threadIdx.x;
    const size_t base = (size_t)blockIdx.x * 32;

    for (int i = 0; i < 4; ++i) {
        int idx = i * 256 + t;
        int n = idx >> 5, c = idx & 31;
        ((float4*)&ms[n][0])[c] = ((const float4*)(A + (base + n) * 128))[c];
        ((float4*)&xs[n][0])[c] = ((const float4*)(x + (base + n) * 128))[c];
    }
    __syncthreads();

    const int j = t & 127;
    const int ng = (t >> 7) * 16;
    float acc[16];
#pragma unroll
    for (int i = 0; i < 16; ++i) acc[i] = 0.0f;

    // GEMM1: k4-blocked, ds_read_b128 broadcasts
    for (int k4 = 0; k4 < 32; ++k4) {
        const int k = k4 * 4;
        float wa0 = W1lT[(k + 0) * 128 + j], wa1 = W1lT[(k + 1) * 128 + j];
        float wa2 = W1lT[(k + 2) * 128 + j], wa3 = W1lT[(k + 3) * 128 + j];
        float wb0 = W1rT[(k + 0) * 128 + j], wb1 = W1rT[(k + 1) * 128 + j];
        float wb2 = W1rT[(k + 2) * 128 + j], wb3 = W1rT[(k + 3) * 128 + j];
#pragma unroll
        for (int i = 0; i < 16; ++i) {
            float4 mv = *(const float4*)&ms[ng + i][k];
            float4 xv = *(const float4*)&xs[ng + i][k];
            acc[i] += mv.x * wa0 + mv.y * wa1 + mv.z * wa2 + mv.w * wa3
                    + xv.x * wb0 + xv.y * wb1 + xv.z * wb2 + xv.w * wb3;
        }
    }
    float bias = b1l[j];
    __syncthreads();                       // all ms/xs reads done
#pragma unroll
    for (int i = 0; i < 16; ++i) xs[ng + i][j] = acc[i] + bias;   // pre-norm out
    __syncthreads();
    {
        int n = t >> 3, lo = (t & 7) * 16;
        float s = 0.0f;
#pragma unroll
        for (int i = 0; i < 16; ++i) { float v = xs[n][lo + i]; s += v * v; }
        s += __shfl_xor(s, 1);
        s += __shfl_xor(s, 2);
        s += __shfl_xor(s, 4);
        if ((t & 7) == 0) scale_s[n] = 1.0f / fmaxf(sqrtf(s), 1e-12f);
    }
    __syncthreads();
    for (int i = 0; i < 16; ++i) {         // h = relu(out*scale) into ms
        int idx = i * 256 + t;
        int n = idx >> 7, c = idx & 127;
        ms[n][c] = fmaxf(xs[n][c] * scale_s[n], 0.0f);
    }
    __syncthreads();

    // GEMM2: tr = [h@W2l.T | h@W2r.T] -> A
#pragma unroll
    for (int i = 0; i < 16; ++i) acc[i] = 0.0f;
    for (int k4 = 0; k4 < 32; ++k4) {
        const int k = k4 * 4;
        float w0 = W2T[(k + 0) * 128 + j], w1 = W2T[(k + 1) * 128 + j];
        float w2 = W2T[(k + 2) * 128 + j], w3 = W2T[(k + 3) * 128 + j];
#pragma unroll
        for (int i = 0; i < 16; ++i) {
            float4 hv = *(const float4*)&ms[ng + i][k];
            acc[i] += hv.x * w0 + hv.y * w1 + hv.z * w2 + hv.w * w3;
        }
    }
#pragma unroll
    for (int i = 0; i < 16; ++i) A[(base + ng + i) * 128 + j] = acc[i];
}

// ---- layer2 gather + bias + self + normalize, one wave/node ----
__global__ __launch_bounds__(256) void l2_final_k(
    const float* __restrict__ A, const int* __restrict__ esrc,
    const int* __restrict__ start, const float* __restrict__ b2l,
    float* __restrict__ out) {
    int n = blockIdx.x * 4 + (threadIdx.x >> 6);   // grid exact NN/4
    int c = threadIdx.x & 63;
    int s0 = start[n], s1 = start[n + 1];
    float a0 = 0.f, a1 = 0.f;
    int e = s0;
    for (; e + 1 < s1; e += 2) {
        a0 += A[(size_t)esrc[e] * 128 + c];
        a1 += A[(size_t)esrc[e + 1] * 128 + c];
    }
    if (e < s1) a0 += A[(size_t)esrc[e] * 128 + c];
    float inv = 1.0f / fmaxf((float)(s1 - s0), 1.0f);
    float v = (a0 + a1) * inv + b2l[c] + A[(size_t)n * 128 + 64 + c];
    float s = v * v;
    for (int o = 1; o < 64; o <<= 1) s += __shfl_xor(s, o);
    out[(size_t)n * 64 + c] = v / fmaxf(sqrtf(s), 1e-12f);
}

extern "C" void kernel_launch(void* const* d_in, const int* in_sizes, int n_in,
                              void* d_out, int out_size, void* d_ws, size_t ws_size,
                              hipStream_t stream) {
    const float* x   = (const float*)d_in[0];
    const int*   ei  = (const int*)d_in[1];
    const float* W1l = (const float*)d_in[2];
    const float* b1l = (const float*)d_in[3];
    const float* W1r = (const float*)d_in[4];
    const float* W2l = (const float*)d_in[5];
    const float* b2l = (const float*)d_in[6];
    const float* W2r = (const float*)d_in[7];
    const int* src = ei;
    const int* dst = ei + NE;
    float* out = (float*)d_out;

    float* A    = (float*)d_ws;                         // N*128
    int*   esrc = (int*)(A + (size_t)NN * 128);         // NE
    int*   start = esrc + NE;                           // N+1
    int*   cnt  = start + NN + 1;                       // N
    int*   fill = cnt + NN;                             // N
    int*   btot = fill + NN;                            // 128
    float* W1lT = (float*)(btot + 128);                 // 128*128
    float* W1rT = W1lT + 128 * 128;
    float* W2T  = W1rT + 128 * 128;

    hipMemsetAsync(cnt, 0, (size_t)NN * sizeof(int), stream);
    hipMemsetAsync(fill, 0, (size_t)NN * sizeof(int), stream);

    prep_w_k<<<64, 256, 0, stream>>>(W1l, W1r, W2l, W2r, W1lT, W1rT, W2T);
    hist_k<<<NE / 256, 256, 0, stream>>>(dst, cnt);
    scan1_k<<<NB_SCAN, 256, 0, stream>>>(cnt, start, btot);
    scan2_k<<<1, 128, 0, stream>>>(btot);
    scan3_k<<<NB_SCAN, 256, 0, stream>>>(start, btot);
    fill_k<<<NE / 256, 256, 0, stream>>>(src, dst, start, fill, esrc);
    agg1_k<<<NN / 4, 256, 0, stream>>>(x, esrc, start, A);
    l12_node_k<<<NN / 32, 256, 0, stream>>>(A, x, W1lT, W1rT, W2T, b1l);
    l2_final_k<<<NN / 4, 256, 0, stream>>>(A, esrc, start, b2l, out);
}

// Round 5
// 501.395 us; speedup vs baseline: 9.0564x; 1.5236x over previous
//
#include <hip/hip_runtime.h>

// GraphSAGE 2-layer forward, MI355X — CSR gather + MFMA (split-bf16) node GEMMs.
// N=100000, E=1600000, F=128, H=128, OUT=64. I/O f32; GEMMs via
// mfma_f32_16x16x32_bf16 with hi/lo bf16 error compensation (~2^-15 rel err).
//
// d_ws layout (16B-aligned sections):
//   buf  : NN*128 f32 region. Per 512B row: agg1 writes [hi bf16 x128 | lo bf16 x128];
//          l12 overwrites same row with tr f32 x128 (in-place, same-block only).
//   P    : 98304 u16 — packed B-fragment weights: [W1l hi|lo][W1r hi|lo][W2 hi|lo],
//          each 16384: frag f=jt*4+ks (j-tile 16, k-step 32), lane, elem.
//   esrc : NE int (src ids bucketed by dst), start : NN+1, cnt/fill : NN, btot : 128

#define NN 100000
#define NE 1600000
#define SCAN_B 1024
#define NB_SCAN ((NN + SCAN_B - 1) / SCAN_B)   // 98

typedef __attribute__((ext_vector_type(8))) short short8;  // 8 bf16 = MFMA A/B frag
typedef __attribute__((ext_vector_type(4))) float f32x4;   // MFMA C/D frag

#define MFMA(a, b, c) c = __builtin_amdgcn_mfma_f32_16x16x32_bf16(a, b, c, 0, 0, 0)
// XOR-swizzle for [32][128] bf16 LDS tiles (256B rows): spreads the 16-lane
// same-column reads across 8 distinct 16B slots (2-way residual = free).
#define LDSWZ(row, bo) (((row) * 256) + ((bo) ^ (((row) & 7) << 4)))

__device__ __forceinline__ unsigned short rne_bf16(float f) {
    unsigned u = __float_as_uint(f);
    unsigned r = u + 0x7FFFu + ((u >> 16) & 1u);
    return (unsigned short)(r >> 16);
}

// split pair (a,b) -> packed hi bf16x2 (truncate) + packed lo bf16x2 (RNE)
__device__ __forceinline__ void split2(float a, float b, unsigned& hi, unsigned& lo) {
    unsigned ua = __float_as_uint(a), ub = __float_as_uint(b);
    hi = (ub & 0xFFFF0000u) | (ua >> 16);
    float la = a - __uint_as_float(ua & 0xFFFF0000u);
    float lb = b - __uint_as_float(ub & 0xFFFF0000u);
    unsigned r;
    asm("v_cvt_pk_bf16_f32 %0, %1, %2" : "=v"(r) : "v"(la), "v"(lb));
    lo = r;
}

// ---- weight pack: B-fragment layout, split hi/lo ----
__global__ void prep_pack_k(const float* __restrict__ W1l, const float* __restrict__ W1r,
                            const float* __restrict__ W2l, const float* __restrict__ W2r,
                            unsigned short* __restrict__ P) {
    int p = blockIdx.x * 256 + threadIdx.x;   // 0..49151 (3 mats x 16384)
    int mat = p / 16384;
    int q = p - mat * 16384;
    int i = q & 7, l = (q >> 3) & 63, f = q >> 9;
    int jt = f >> 2, ks = f & 3;
    int j = jt * 16 + (l & 15);
    int k = ks * 32 + (l >> 4) * 8 + i;
    float w;
    if (mat == 0)      w = W1l[j * 128 + k];
    else if (mat == 1) w = W1r[j * 128 + k];
    else               w = (j < 64) ? W2l[j * 128 + k] : W2r[(j - 64) * 128 + k];
    unsigned short hi = rne_bf16(w);
    float whi = __uint_as_float(((unsigned)hi) << 16);
    unsigned short lo = rne_bf16(w - whi);
    P[mat * 32768 + q] = hi;
    P[mat * 32768 + 16384 + q] = lo;
}

// ---- degree histogram ----
__global__ void hist_k(const int* __restrict__ dst, int* __restrict__ cnt) {
    int e = blockIdx.x * 256 + threadIdx.x;
    atomicAdd(&cnt[dst[e]], 1);
}

// ---- exclusive scan (3 passes) ----
__global__ void scan1_k(const int* __restrict__ cnt, int* __restrict__ start,
                        int* __restrict__ btot) {
    __shared__ int sd[256];
    int b = blockIdx.x, t = threadIdx.x;
    int base = b * SCAN_B + t * 4;
    int v0 = (base + 0 < NN) ? cnt[base + 0] : 0;
    int v1 = (base + 1 < NN) ? cnt[base + 1] : 0;
    int v2 = (base + 2 < NN) ? cnt[base + 2] : 0;
    int v3 = (base + 3 < NN) ? cnt[base + 3] : 0;
    int sum = v0 + v1 + v2 + v3;
    sd[t] = sum;
    __syncthreads();
    for (int o = 1; o < 256; o <<= 1) {
        int x = (t >= o) ? sd[t - o] : 0;
        __syncthreads();
        sd[t] += x;
        __syncthreads();
    }
    int run = sd[t] - sum;
    if (base + 0 < NN) start[base + 0] = run; run += v0;
    if (base + 1 < NN) start[base + 1] = run; run += v1;
    if (base + 2 < NN) start[base + 2] = run; run += v2;
    if (base + 3 < NN) start[base + 3] = run;
    if (t == 255) btot[b] = sd[255];
}

__global__ void scan2_k(int* __restrict__ btot) {
    __shared__ int sd[128];
    int t = threadIdx.x;
    int v = (t < NB_SCAN) ? btot[t] : 0;
    sd[t] = v;
    __syncthreads();
    for (int o = 1; o < 128; o <<= 1) {
        int x = (t >= o) ? sd[t - o] : 0;
        __syncthreads();
        sd[t] += x;
        __syncthreads();
    }
    if (t < NB_SCAN) btot[t] = sd[t] - v;
}

__global__ void scan3_k(int* __restrict__ start, const int* __restrict__ btot) {
    int b = blockIdx.x;
    int off = btot[b];
    int base = b * SCAN_B + threadIdx.x;
#pragma unroll
    for (int i = 0; i < 4; ++i) {
        int idx = base + i * 256;
        if (idx < NN) start[idx] += off;
    }
    if (b == 0 && threadIdx.x == 0) start[NN] = NE;
}

// ---- bucket fill ----
__global__ void fill_k(const int* __restrict__ src, const int* __restrict__ dst,
                       const int* __restrict__ start, int* __restrict__ fill,
                       int* __restrict__ esrc) {
    int e = blockIdx.x * 256 + threadIdx.x;
    int d = dst[e];
    int pos = start[d] + atomicAdd(&fill[d], 1);
    esrc[pos] = src[e];
}

// ---- layer1 gather: mean of x[src] per node, output split-bf16 row [hi|lo].
//      1 wave/node, 4 independent accumulator chains for MLP. ----
__global__ __launch_bounds__(256) void agg1_k(const float* __restrict__ x,
                                              const int* __restrict__ esrc,
                                              const int* __restrict__ start,
                                              char* __restrict__ buf) {
    int n = blockIdx.x * 4 + (threadIdx.x >> 6);   // grid exact NN/4
    int lane = threadIdx.x & 63;
    int s0 = start[n], s1 = start[n + 1];
    float2 a0 = {0.f, 0.f}, a1 = {0.f, 0.f}, a2 = {0.f, 0.f}, a3 = {0.f, 0.f};
    int e = s0;
    for (; e + 3 < s1; e += 4) {
        int sa = esrc[e], sb = esrc[e + 1], sc = esrc[e + 2], sd = esrc[e + 3];
        float2 va = *(const float2*)(x + (size_t)sa * 128 + lane * 2);
        float2 vb = *(const float2*)(x + (size_t)sb * 128 + lane * 2);
        float2 vc = *(const float2*)(x + (size_t)sc * 128 + lane * 2);
        float2 vd = *(const float2*)(x + (size_t)sd * 128 + lane * 2);
        a0.x += va.x; a0.y += va.y; a1.x += vb.x; a1.y += vb.y;
        a2.x += vc.x; a2.y += vc.y; a3.x += vd.x; a3.y += vd.y;
    }
    for (; e < s1; ++e) {
        int sa = esrc[e];
        float2 va = *(const float2*)(x + (size_t)sa * 128 + lane * 2);
        a0.x += va.x; a0.y += va.y;
    }
    float inv = 1.0f / fmaxf((float)(s1 - s0), 1.0f);
    float m0 = (a0.x + a1.x + a2.x + a3.x) * inv;
    float m1 = (a0.y + a1.y + a2.y + a3.y) * inv;
    unsigned hi, lo;
    split2(m0, m1, hi, lo);
    char* row = buf + (size_t)n * 512;
    ((unsigned*)row)[lane] = hi;
    ((unsigned*)(row + 256))[lane] = lo;
}

// ---- fused node kernel (MFMA): h = relu(norm(mean@W1l.T + b1l + x@W1r.T));
//      buf row <- tr f32 = [h@W2l.T | h@W2r.T].  32 nodes/block, 4 waves.
//      Wave w owns j in [32w, 32w+32) (2 j-tiles); 2 m-tiles of 16. ----
__global__ __launch_bounds__(256, 3) void l12_node_k(
    float* __restrict__ buf, const float* __restrict__ x,
    const unsigned short* __restrict__ P, const float* __restrict__ b1l) {
    __shared__ unsigned short msh_s[32 * 128];   // mean hi -> h hi
    __shared__ unsigned short msl_s[32 * 128];   // mean lo -> h lo
    __shared__ unsigned short xsh_s[32 * 128];   // x hi
    __shared__ unsigned short xsl_s[32 * 128];   // x lo
    __shared__ float outs_s[32 * 136];           // GEMM1 out (pad 136 vs conflicts)
    __shared__ float scale_s[32];

    const int t = threadIdx.x;
    const size_t gbase = (size_t)blockIdx.x * 32;

    // ---- stage: mean (already split) copy + x split-convert ----
    {
        const int row = t >> 3, c = t & 7;       // 32 rows x 8 chunks x 16 elems
        const char* brow = (const char*)buf + (gbase + row) * 512;
        int4 mh0 = *(const int4*)(brow + c * 32);
        int4 mh1 = *(const int4*)(brow + c * 32 + 16);
        int4 ml0 = *(const int4*)(brow + 256 + c * 32);
        int4 ml1 = *(const int4*)(brow + 256 + c * 32 + 16);
        *(int4*)((char*)msh_s + LDSWZ(row, c * 32)) = mh0;
        *(int4*)((char*)msh_s + LDSWZ(row, c * 32 + 16)) = mh1;
        *(int4*)((char*)msl_s + LDSWZ(row, c * 32)) = ml0;
        *(int4*)((char*)msl_s + LDSWZ(row, c * 32 + 16)) = ml1;

        const float* xrow = x + (gbase + row) * 128 + c * 16;
        unsigned h[8], l[8];
#pragma unroll
        for (int q = 0; q < 4; ++q) {
            float4 v = *(const float4*)(xrow + 4 * q);
            split2(v.x, v.y, h[2 * q], l[2 * q]);
            split2(v.z, v.w, h[2 * q + 1], l[2 * q + 1]);
        }
        int4 hv0 = {(int)h[0], (int)h[1], (int)h[2], (int)h[3]};
        int4 hv1 = {(int)h[4], (int)h[5], (int)h[6], (int)h[7]};
        int4 lv0 = {(int)l[0], (int)l[1], (int)l[2], (int)l[3]};
        int4 lv1 = {(int)l[4], (int)l[5], (int)l[6], (int)l[7]};
        *(int4*)((char*)xsh_s + LDSWZ(row, c * 32)) = hv0;
        *(int4*)((char*)xsh_s + LDSWZ(row, c * 32 + 16)) = hv1;
        *(int4*)((char*)xsl_s + LDSWZ(row, c * 32)) = lv0;
        *(int4*)((char*)xsl_s + LDSWZ(row, c * 32 + 16)) = lv1;
    }
    __syncthreads();

    const int lane = t & 63;
    const int wv = t >> 6;
    const int l15 = lane & 15;
    const int l4 = lane >> 4;
    const unsigned short* Wp1l_h = P;
    const unsigned short* Wp1l_l = P + 16384;
    const unsigned short* Wp1r_h = P + 32768;
    const unsigned short* Wp1r_l = P + 49152;
    const unsigned short* Wp2_h  = P + 65536;
    const unsigned short* Wp2_l  = P + 81920;

    // ---- GEMM1: out = mean@W1l.T + x@W1r.T (3-term split products) ----
    f32x4 acc00 = {0.f, 0.f, 0.f, 0.f}, acc01 = acc00, acc10 = acc00, acc11 = acc00;
#pragma unroll
    for (int ks = 0; ks < 4; ++ks) {
        const int abo = ks * 64 + (l4 << 4);
        const short8 amh0 = *(const short8*)((const char*)msh_s + LDSWZ(l15, abo));
        const short8 amh1 = *(const short8*)((const char*)msh_s + LDSWZ(l15 + 16, abo));
        const short8 aml0 = *(const short8*)((const char*)msl_s + LDSWZ(l15, abo));
        const short8 aml1 = *(const short8*)((const char*)msl_s + LDSWZ(l15 + 16, abo));
        const short8 axh0 = *(const short8*)((const char*)xsh_s + LDSWZ(l15, abo));
        const short8 axh1 = *(const short8*)((const char*)xsh_s + LDSWZ(l15 + 16, abo));
        const short8 axl0 = *(const short8*)((const char*)xsl_s + LDSWZ(l15, abo));
        const short8 axl1 = *(const short8*)((const char*)xsl_s + LDSWZ(l15 + 16, abo));
        const int o0 = ((2 * wv) * 4 + ks) * 512 + lane * 8;
        const int o1 = ((2 * wv + 1) * 4 + ks) * 512 + lane * 8;
        const short8 blh0 = *(const short8*)(Wp1l_h + o0);
        const short8 bll0 = *(const short8*)(Wp1l_l + o0);
        const short8 brh0 = *(const short8*)(Wp1r_h + o0);
        const short8 brl0 = *(const short8*)(Wp1r_l + o0);
        const short8 blh1 = *(const short8*)(Wp1l_h + o1);
        const short8 bll1 = *(const short8*)(Wp1l_l + o1);
        const short8 brh1 = *(const short8*)(Wp1r_h + o1);
        const short8 brl1 = *(const short8*)(Wp1r_l + o1);
        MFMA(amh0, blh0, acc00); MFMA(aml0, blh0, acc00); MFMA(amh0, bll0, acc00);
        MFMA(axh0, brh0, acc00); MFMA(axl0, brh0, acc00); MFMA(axh0, brl0, acc00);
        MFMA(amh1, blh0, acc10); MFMA(aml1, blh0, acc10); MFMA(amh1, bll0, acc10);
        MFMA(axh1, brh0, acc10); MFMA(axl1, brh0, acc10); MFMA(axh1, brl0, acc10);
        MFMA(amh0, blh1, acc01); MFMA(aml0, blh1, acc01); MFMA(amh0, bll1, acc01);
        MFMA(axh0, brh1, acc01); MFMA(axl0, brh1, acc01); MFMA(axh0, brl1, acc01);
        MFMA(amh1, blh1, acc11); MFMA(aml1, blh1, acc11); MFMA(amh1, bll1, acc11);
        MFMA(axh1, brh1, acc11); MFMA(axl1, brh1, acc11); MFMA(axh1, brl1, acc11);
    }
    {   // epilogue: C layout col=lane&15, row=(lane>>4)*4+r
        float bi0 = b1l[wv * 32 + l15];
        float bi1 = b1l[wv * 32 + 16 + l15];
#pragma unroll
        for (int r2 = 0; r2 < 4; ++r2) {
            int m0 = l4 * 4 + r2;
            outs_s[m0 * 136 + wv * 32 + l15]             = acc00[r2] + bi0;
            outs_s[m0 * 136 + wv * 32 + 16 + l15]        = acc01[r2] + bi1;
            outs_s[(m0 + 16) * 136 + wv * 32 + l15]      = acc10[r2] + bi0;
            outs_s[(m0 + 16) * 136 + wv * 32 + 16 + l15] = acc11[r2] + bi1;
        }
    }
    __syncthreads();

    // ---- row norms (8 lanes per node) ----
    {
        const int n = t >> 3, lo16 = (t & 7) * 16;
        const float4* op = (const float4*)(outs_s + n * 136 + lo16);
        float s = 0.f;
#pragma unroll
        for (int q = 0; q < 4; ++q) {
            float4 v = op[q];
            s += v.x * v.x + v.y * v.y + v.z * v.z + v.w * v.w;
        }
        s += __shfl_xor(s, 1);
        s += __shfl_xor(s, 2);
        s += __shfl_xor(s, 4);
        if ((t & 7) == 0) scale_s[n] = 1.0f / fmaxf(sqrtf(s), 1e-12f);
    }
    __syncthreads();

    // ---- h = relu(out*scale), split-convert into msh/msl ----
    {
        const int row = t >> 3, c = t & 7;
        const float sc = scale_s[row];
        const float4* op = (const float4*)(outs_s + row * 136 + c * 16);
        unsigned h[8], l[8];
#pragma unroll
        for (int q = 0; q < 4; ++q) {
            float4 v = op[q];
            float a0 = fmaxf(v.x * sc, 0.f), a1 = fmaxf(v.y * sc, 0.f);
            float a2 = fmaxf(v.z * sc, 0.f), a3 = fmaxf(v.w * sc, 0.f);
            split2(a0, a1, h[2 * q], l[2 * q]);
            split2(a2, a3, h[2 * q + 1], l[2 * q + 1]);
        }
        int4 hv0 = {(int)h[0], (int)h[1], (int)h[2], (int)h[3]};
        int4 hv1 = {(int)h[4], (int)h[5], (int)h[6], (int)h[7]};
        int4 lv0 = {(int)l[0], (int)l[1], (int)l[2], (int)l[3]};
        int4 lv1 = {(int)l[4], (int)l[5], (int)l[6], (int)l[7]};
        *(int4*)((char*)msh_s + LDSWZ(row, c * 32)) = hv0;
        *(int4*)((char*)msh_s + LDSWZ(row, c * 32 + 16)) = hv1;
        *(int4*)((char*)msl_s + LDSWZ(row, c * 32)) = lv0;
        *(int4*)((char*)msl_s + LDSWZ(row, c * 32 + 16)) = lv1;
    }
    __syncthreads();

    // ---- GEMM2: tr = h @ [W2l|W2r].T -> buf rows (f32, in place) ----
    f32x4 c00 = {0.f, 0.f, 0.f, 0.f}, c01 = c00, c10 = c00, c11 = c00;
#pragma unroll
    for (int ks = 0; ks < 4; ++ks) {
        const int abo = ks * 64 + (l4 << 4);
        const short8 ah0 = *(const short8*)((const char*)msh_s + LDSWZ(l15, abo));
        const short8 ah1 = *(const short8*)((const char*)msh_s + LDSWZ(l15 + 16, abo));
        const short8 al0 = *(const short8*)((const char*)msl_s + LDSWZ(l15, abo));
        const short8 al1 = *(const short8*)((const char*)msl_s + LDSWZ(l15 + 16, abo));
        const int o0 = ((2 * wv) * 4 + ks) * 512 + lane * 8;
        const int o1 = ((2 * wv + 1) * 4 + ks) * 512 + lane * 8;
        const short8 bh0 = *(const short8*)(Wp2_h + o0);
        const short8 bl0 = *(const short8*)(Wp2_l + o0);
        const short8 bh1 = *(const short8*)(Wp2_h + o1);
        const short8 bl1 = *(const short8*)(Wp2_l + o1);
        MFMA(ah0, bh0, c00); MFMA(al0, bh0, c00); MFMA(ah0, bl0, c00);
        MFMA(ah1, bh0, c10); MFMA(al1, bh0, c10); MFMA(ah1, bl0, c10);
        MFMA(ah0, bh1, c01); MFMA(al0, bh1, c01); MFMA(ah0, bl1, c01);
        MFMA(ah1, bh1, c11); MFMA(al1, bh1, c11); MFMA(ah1, bl1, c11);
    }
    {
#pragma unroll
        for (int r2 = 0; r2 < 4; ++r2) {
            int m0 = l4 * 4 + r2;
            buf[(gbase + m0) * 128 + wv * 32 + l15]             = c00[r2];
            buf[(gbase + m0) * 128 + wv * 32 + 16 + l15]        = c01[r2];
            buf[(gbase + m0 + 16) * 128 + wv * 32 + l15]        = c10[r2];
            buf[(gbase + m0 + 16) * 128 + wv * 32 + 16 + l15]   = c11[r2];
        }
    }
}

// ---- layer2 gather + bias + self + normalize (4-chain unroll) ----
__global__ __launch_bounds__(256) void l2_final_k(
    const float* __restrict__ A, const int* __restrict__ esrc,
    const int* __restrict__ start, const float* __restrict__ b2l,
    float* __restrict__ out) {
    int n = blockIdx.x * 4 + (threadIdx.x >> 6);   // grid exact NN/4
    int c = threadIdx.x & 63;
    int s0 = start[n], s1 = start[n + 1];
    float a0 = 0.f, a1 = 0.f, a2 = 0.f, a3 = 0.f;
    int e = s0;
    for (; e + 3 < s1; e += 4) {
        a0 += A[(size_t)esrc[e] * 128 + c];
        a1 += A[(size_t)esrc[e + 1] * 128 + c];
        a2 += A[(size_t)esrc[e + 2] * 128 + c];
        a3 += A[(size_t)esrc[e + 3] * 128 + c];
    }
    for (; e < s1; ++e) a0 += A[(size_t)esrc[e] * 128 + c];
    float inv = 1.0f / fmaxf((float)(s1 - s0), 1.0f);
    float v = (a0 + a1 + a2 + a3) * inv + b2l[c] + A[(size_t)n * 128 + 64 + c];
    float s = v * v;
    for (int o = 1; o < 64; o <<= 1) s += __shfl_xor(s, o);
    out[(size_t)n * 64 + c] = v / fmaxf(sqrtf(s), 1e-12f);
}

extern "C" void kernel_launch(void* const* d_in, const int* in_sizes, int n_in,
                              void* d_out, int out_size, void* d_ws, size_t ws_size,
                              hipStream_t stream) {
    const float* x   = (const float*)d_in[0];
    const int*   ei  = (const int*)d_in[1];
    const float* W1l = (const float*)d_in[2];
    const float* b1l = (const float*)d_in[3];
    const float* W1r = (const float*)d_in[4];
    const float* W2l = (const float*)d_in[5];
    const float* b2l = (const float*)d_in[6];
    const float* W2r = (const float*)d_in[7];
    const int* src = ei;
    const int* dst = ei + NE;
    float* out = (float*)d_out;

    float* buf = (float*)d_ws;                                    // NN*128 f32
    unsigned short* P = (unsigned short*)(buf + (size_t)NN * 128); // 98304 u16 (16B-aligned)
    int* esrc  = (int*)(P + 98304);                               // NE
    int* start = esrc + NE;                                       // NN+1
    int* cnt   = start + NN + 1;                                  // NN
    int* fill  = cnt + NN;                                        // NN
    int* btot  = fill + NN;                                       // 128

    hipMemsetAsync(cnt, 0, (size_t)NN * sizeof(int), stream);
    hipMemsetAsync(fill, 0, (size_t)NN * sizeof(int), stream);

    prep_pack_k<<<192, 256, 0, stream>>>(W1l, W1r, W2l, W2r, P);
    hist_k<<<NE / 256, 256, 0, stream>>>(dst, cnt);
    scan1_k<<<NB_SCAN, 256, 0, stream>>>(cnt, start, btot);
    scan2_k<<<1, 128, 0, stream>>>(btot);
    scan3_k<<<NB_SCAN, 256, 0, stream>>>(start, btot);
    fill_k<<<NE / 256, 256, 0, stream>>>(src, dst, start, fill, esrc);
    agg1_k<<<NN / 4, 256, 0, stream>>>(x, esrc, start, (char*)buf);
    l12_node_k<<<NN / 32, 256, 0, stream>>>(buf, x, P, b1l);
    l2_final_k<<<NN / 4, 256, 0, stream>>>(buf, esrc, start, b2l, out);
}

// Round 7
// 421.303 us; speedup vs baseline: 10.7781x; 1.1901x over previous
//
#include <hip/hip_runtime.h>

// GraphSAGE 2-layer forward, MI355X — CSR gather (atomic-free fill) +
// MFMA split-bf16 node GEMMs + bf16-compact gather buffers.
// N=100000, E=1600000, F=128, H=128, OUT=64.
//
// d_ws layout:
//   buf  : NN*128 f32. Per 512B row: agg1 writes [mean hi bf16 x128 | lo x128];
//          l12 overwrites bytes 0..255 with self f32 x64 (h@W2r.T).
//   P    : 98304 u16 packed B-fragment weights [W1l hi|lo][W1r hi|lo][W2 hi|lo]
//   esrc : NE int (src ids bucketed by dst)
//   start: NN+1 int,  cnt: NN int,  btot: 128 int
//   trbf : NN*64 u16 (h@W2l.T bf16, written by l12) — doubles as rank[NE] int
//          during the CSR build (consumed by fill_k before l12 runs).
// d_out doubles as xbf (NN*64 uint = bf16x2 copy of x) until l2_final writes it.

#define NN 100000
#define NE 1600000
#define SCAN_B 1024
#define NB_SCAN ((NN + SCAN_B - 1) / SCAN_B)   // 98

typedef __attribute__((ext_vector_type(8))) short short8;
typedef __attribute__((ext_vector_type(4))) float f32x4;

#define MFMA(a, b, c) c = __builtin_amdgcn_mfma_f32_16x16x32_bf16(a, b, c, 0, 0, 0)
#define LDSWZ(row, bo) (((row) * 256) + ((bo) ^ (((row) & 7) << 4)))

__device__ __forceinline__ unsigned short rne_bf16(float f) {
    unsigned u = __float_as_uint(f);
    unsigned r = u + 0x7FFFu + ((u >> 16) & 1u);
    return (unsigned short)(r >> 16);
}

// split pair (a,b) -> hi (truncate, a in low16) + lo (RNE of residual)
__device__ __forceinline__ void split2(float a, float b, unsigned& hi, unsigned& lo) {
    unsigned ua = __float_as_uint(a), ub = __float_as_uint(b);
    hi = (ub & 0xFFFF0000u) | (ua >> 16);
    float la = a - __uint_as_float(ua & 0xFFFF0000u);
    float lb = b - __uint_as_float(ub & 0xFFFF0000u);
    lo = ((unsigned)rne_bf16(lb) << 16) | rne_bf16(la);
}

// ---- x -> bf16x2 copy (for agg1 gather), 8 elems/thread ----
__global__ void xconv_k(const float* __restrict__ x, unsigned* __restrict__ xbf) {
    int t = blockIdx.x * 256 + threadIdx.x;   // grid exact NN*16/256
    const float4* p = (const float4*)(x + (size_t)t * 8);
    float4 v0 = p[0], v1 = p[1];
    uint4 r;
    r.x = ((unsigned)rne_bf16(v0.y) << 16) | rne_bf16(v0.x);
    r.y = ((unsigned)rne_bf16(v0.w) << 16) | rne_bf16(v0.z);
    r.z = ((unsigned)rne_bf16(v1.y) << 16) | rne_bf16(v1.x);
    r.w = ((unsigned)rne_bf16(v1.w) << 16) | rne_bf16(v1.z);
    *(uint4*)(xbf + (size_t)t * 4) = r;
}

// ---- weight pack: B-fragment layout, split hi/lo ----
__global__ void prep_pack_k(const float* __restrict__ W1l, const float* __restrict__ W1r,
                            const float* __restrict__ W2l, const float* __restrict__ W2r,
                            unsigned short* __restrict__ P) {
    int p = blockIdx.x * 256 + threadIdx.x;   // 0..49151
    int mat = p / 16384;
    int q = p - mat * 16384;
    int i = q & 7, l = (q >> 3) & 63, f = q >> 9;
    int jt = f >> 2, ks = f & 3;
    int j = jt * 16 + (l & 15);
    int k = ks * 32 + (l >> 4) * 8 + i;
    float w;
    if (mat == 0)      w = W1l[j * 128 + k];
    else if (mat == 1) w = W1r[j * 128 + k];
    else               w = (j < 64) ? W2l[j * 128 + k] : W2r[(j - 64) * 128 + k];
    unsigned short hi = rne_bf16(w);
    float whi = __uint_as_float(((unsigned)hi) << 16);
    unsigned short lo = rne_bf16(w - whi);
    P[mat * 32768 + q] = hi;
    P[mat * 32768 + 16384 + q] = lo;
}

// ---- degree histogram + per-edge rank (atomic return value) ----
__global__ void rank_k(const int* __restrict__ dst, int* __restrict__ cnt,
                       int* __restrict__ rank) {
    int e = blockIdx.x * 256 + threadIdx.x;
    rank[e] = atomicAdd(&cnt[dst[e]], 1);
}

// ---- exclusive scan (3 passes) ----
__global__ void scan1_k(const int* __restrict__ cnt, int* __restrict__ start,
                        int* __restrict__ btot) {
    __shared__ int sd[256];
    int b = blockIdx.x, t = threadIdx.x;
    int base = b * SCAN_B + t * 4;
    int v0 = (base + 0 < NN) ? cnt[base + 0] : 0;
    int v1 = (base + 1 < NN) ? cnt[base + 1] : 0;
    int v2 = (base + 2 < NN) ? cnt[base + 2] : 0;
    int v3 = (base + 3 < NN) ? cnt[base + 3] : 0;
    int sum = v0 + v1 + v2 + v3;
    sd[t] = sum;
    __syncthreads();
    for (int o = 1; o < 256; o <<= 1) {
        int x = (t >= o) ? sd[t - o] : 0;
        __syncthreads();
        sd[t] += x;
        __syncthreads();
    }
    int run = sd[t] - sum;
    if (base + 0 < NN) start[base + 0] = run; run += v0;
    if (base + 1 < NN) start[base + 1] = run; run += v1;
    if (base + 2 < NN) start[base + 2] = run; run += v2;
    if (base + 3 < NN) start[base + 3] = run;
    if (t == 255) btot[b] = sd[255];
}

__global__ void scan2_k(int* __restrict__ btot) {
    __shared__ int sd[128];
    int t = threadIdx.x;
    int v = (t < NB_SCAN) ? btot[t] : 0;
    sd[t] = v;
    __syncthreads();
    for (int o = 1; o < 128; o <<= 1) {
        int x = (t >= o) ? sd[t - o] : 0;
        __syncthreads();
        sd[t] += x;
        __syncthreads();
    }
    if (t < NB_SCAN) btot[t] = sd[t] - v;
}

__global__ void scan3_k(int* __restrict__ start, const int* __restrict__ btot) {
    int b = blockIdx.x;
    int off = btot[b];
    int base = b * SCAN_B + threadIdx.x;
#pragma unroll
    for (int i = 0; i < 4; ++i) {
        int idx = base + i * 256;
        if (idx < NN) start[idx] += off;
    }
    if (b == 0 && threadIdx.x == 0) start[NN] = NE;
}

// ---- bucket fill (no atomics) ----
__global__ void fill_k(const int* __restrict__ src, const int* __restrict__ dst,
                       const int* __restrict__ start, const int* __restrict__ rank,
                       int* __restrict__ esrc) {
    int e = blockIdx.x * 256 + threadIdx.x;
    esrc[start[dst[e]] + rank[e]] = src[e];
}

// ---- layer1 gather (bf16 x): mean per node -> split hi/lo row in buf ----
__global__ __launch_bounds__(256) void agg1_k(const unsigned* __restrict__ xbf,
                                              const int* __restrict__ esrc,
                                              const int* __restrict__ start,
                                              char* __restrict__ buf) {
    int n = blockIdx.x * 4 + (threadIdx.x >> 6);   // grid exact NN/4
    int lane = threadIdx.x & 63;
    int s0 = start[n], s1 = start[n + 1];
    float a0x = 0.f, a0y = 0.f, a1x = 0.f, a1y = 0.f;
    float a2x = 0.f, a2y = 0.f, a3x = 0.f, a3y = 0.f;
    int e = s0;
    for (; e + 3 < s1; e += 4) {
        unsigned va = xbf[(size_t)esrc[e] * 64 + lane];
        unsigned vb = xbf[(size_t)esrc[e + 1] * 64 + lane];
        unsigned vc = xbf[(size_t)esrc[e + 2] * 64 + lane];
        unsigned vd = xbf[(size_t)esrc[e + 3] * 64 + lane];
        a0x += __uint_as_float(va << 16); a0y += __uint_as_float(va & 0xFFFF0000u);
        a1x += __uint_as_float(vb << 16); a1y += __uint_as_float(vb & 0xFFFF0000u);
        a2x += __uint_as_float(vc << 16); a2y += __uint_as_float(vc & 0xFFFF0000u);
        a3x += __uint_as_float(vd << 16); a3y += __uint_as_float(vd & 0xFFFF0000u);
    }
    for (; e < s1; ++e) {
        unsigned va = xbf[(size_t)esrc[e] * 64 + lane];
        a0x += __uint_as_float(va << 16); a0y += __uint_as_float(va & 0xFFFF0000u);
    }
    float inv = 1.0f / fmaxf((float)(s1 - s0), 1.0f);
    float m0 = (a0x + a1x + a2x + a3x) * inv;
    float m1 = (a0y + a1y + a2y + a3y) * inv;
    unsigned hi, lo;
    split2(m0, m1, hi, lo);
    char* row = buf + (size_t)n * 512;
    ((unsigned*)row)[lane] = hi;
    ((unsigned*)(row + 256))[lane] = lo;
}

// ---- fused node kernel (MFMA): h = relu(norm(mean@W1l.T + b1l + x@W1r.T));
//      trbf <- bf16(h@W2l.T); buf row bytes 0..255 <- f32(h@W2r.T). ----
__global__ __launch_bounds__(256, 3) void l12_node_k(
    float* __restrict__ buf, const float* __restrict__ x,
    const unsigned short* __restrict__ P, const float* __restrict__ b1l,
    unsigned short* __restrict__ trbf) {
    __shared__ unsigned short msh_s[32 * 128];
    __shared__ unsigned short msl_s[32 * 128];
    __shared__ unsigned short xsh_s[32 * 128];
    __shared__ unsigned short xsl_s[32 * 128];
    __shared__ float outs_s[32 * 136];
    __shared__ float scale_s[32];

    const int t = threadIdx.x;
    const size_t gbase = (size_t)blockIdx.x * 32;

    {   // stage: mean copy + x split-convert
        const int row = t >> 3, c = t & 7;
        const char* brow = (const char*)buf + (gbase + row) * 512;
        int4 mh0 = *(const int4*)(brow + c * 32);
        int4 mh1 = *(const int4*)(brow + c * 32 + 16);
        int4 ml0 = *(const int4*)(brow + 256 + c * 32);
        int4 ml1 = *(const int4*)(brow + 256 + c * 32 + 16);
        *(int4*)((char*)msh_s + LDSWZ(row, c * 32)) = mh0;
        *(int4*)((char*)msh_s + LDSWZ(row, c * 32 + 16)) = mh1;
        *(int4*)((char*)msl_s + LDSWZ(row, c * 32)) = ml0;
        *(int4*)((char*)msl_s + LDSWZ(row, c * 32 + 16)) = ml1;

        const float* xrow = x + (gbase + row) * 128 + c * 16;
        unsigned h[8], l[8];
#pragma unroll
        for (int q = 0; q < 4; ++q) {
            float4 v = *(const float4*)(xrow + 4 * q);
            split2(v.x, v.y, h[2 * q], l[2 * q]);
            split2(v.z, v.w, h[2 * q + 1], l[2 * q + 1]);
        }
        int4 hv0 = {(int)h[0], (int)h[1], (int)h[2], (int)h[3]};
        int4 hv1 = {(int)h[4], (int)h[5], (int)h[6], (int)h[7]};
        int4 lv0 = {(int)l[0], (int)l[1], (int)l[2], (int)l[3]};
        int4 lv1 = {(int)l[4], (int)l[5], (int)l[6], (int)l[7]};
        *(int4*)((char*)xsh_s + LDSWZ(row, c * 32)) = hv0;
        *(int4*)((char*)xsh_s + LDSWZ(row, c * 32 + 16)) = hv1;
        *(int4*)((char*)xsl_s + LDSWZ(row, c * 32)) = lv0;
        *(int4*)((char*)xsl_s + LDSWZ(row, c * 32 + 16)) = lv1;
    }
    __syncthreads();

    const int lane = t & 63;
    const int wv = t >> 6;
    const int l15 = lane & 15;
    const int l4 = lane >> 4;
    const unsigned short* Wp1l_h = P;
    const unsigned short* Wp1l_l = P + 16384;
    const unsigned short* Wp1r_h = P + 32768;
    const unsigned short* Wp1r_l = P + 49152;
    const unsigned short* Wp2_h  = P + 65536;
    const unsigned short* Wp2_l  = P + 81920;

    // GEMM1
    f32x4 acc00 = {0.f, 0.f, 0.f, 0.f}, acc01 = acc00, acc10 = acc00, acc11 = acc00;
#pragma unroll
    for (int ks = 0; ks < 4; ++ks) {
        const int abo = ks * 64 + (l4 << 4);
        const short8 amh0 = *(const short8*)((const char*)msh_s + LDSWZ(l15, abo));
        const short8 amh1 = *(const short8*)((const char*)msh_s + LDSWZ(l15 + 16, abo));
        const short8 aml0 = *(const short8*)((const char*)msl_s + LDSWZ(l15, abo));
        const short8 aml1 = *(const short8*)((const char*)msl_s + LDSWZ(l15 + 16, abo));
        const short8 axh0 = *(const short8*)((const char*)xsh_s + LDSWZ(l15, abo));
        const short8 axh1 = *(const short8*)((const char*)xsh_s + LDSWZ(l15 + 16, abo));
        const short8 axl0 = *(const short8*)((const char*)xsl_s + LDSWZ(l15, abo));
        const short8 axl1 = *(const short8*)((const char*)xsl_s + LDSWZ(l15 + 16, abo));
        const int o0 = ((2 * wv) * 4 + ks) * 512 + lane * 8;
        const int o1 = ((2 * wv + 1) * 4 + ks) * 512 + lane * 8;
        const short8 blh0 = *(const short8*)(Wp1l_h + o0);
        const short8 bll0 = *(const short8*)(Wp1l_l + o0);
        const short8 brh0 = *(const short8*)(Wp1r_h + o0);
        const short8 brl0 = *(const short8*)(Wp1r_l + o0);
        const short8 blh1 = *(const short8*)(Wp1l_h + o1);
        const short8 bll1 = *(const short8*)(Wp1l_l + o1);
        const short8 brh1 = *(const short8*)(Wp1r_h + o1);
        const short8 brl1 = *(const short8*)(Wp1r_l + o1);
        MFMA(amh0, blh0, acc00); MFMA(aml0, blh0, acc00); MFMA(amh0, bll0, acc00);
        MFMA(axh0, brh0, acc00); MFMA(axl0, brh0, acc00); MFMA(axh0, brl0, acc00);
        MFMA(amh1, blh0, acc10); MFMA(aml1, blh0, acc10); MFMA(amh1, bll0, acc10);
        MFMA(axh1, brh0, acc10); MFMA(axl1, brh0, acc10); MFMA(axh1, brl0, acc10);
        MFMA(amh0, blh1, acc01); MFMA(aml0, blh1, acc01); MFMA(amh0, bll1, acc01);
        MFMA(axh0, brh1, acc01); MFMA(axl0, brh1, acc01); MFMA(axh0, brl1, acc01);
        MFMA(amh1, blh1, acc11); MFMA(aml1, blh1, acc11); MFMA(amh1, bll1, acc11);
        MFMA(axh1, brh1, acc11); MFMA(axl1, brh1, acc11); MFMA(axh1, brl1, acc11);
    }
    {
        float bi0 = b1l[wv * 32 + l15];
        float bi1 = b1l[wv * 32 + 16 + l15];
#pragma unroll
        for (int r2 = 0; r2 < 4; ++r2) {
            int m0 = l4 * 4 + r2;
            outs_s[m0 * 136 + wv * 32 + l15]             = acc00[r2] + bi0;
            outs_s[m0 * 136 + wv * 32 + 16 + l15]        = acc01[r2] + bi1;
            outs_s[(m0 + 16) * 136 + wv * 32 + l15]      = acc10[r2] + bi0;
            outs_s[(m0 + 16) * 136 + wv * 32 + 16 + l15] = acc11[r2] + bi1;
        }
    }
    __syncthreads();

    {   // row norms
        const int n = t >> 3, lo16 = (t & 7) * 16;
        const float4* op = (const float4*)(outs_s + n * 136 + lo16);
        float s = 0.f;
#pragma unroll
        for (int q = 0; q < 4; ++q) {
            float4 v = op[q];
            s += v.x * v.x + v.y * v.y + v.z * v.z + v.w * v.w;
        }
        s += __shfl_xor(s, 1);
        s += __shfl_xor(s, 2);
        s += __shfl_xor(s, 4);
        if ((t & 7) == 0) scale_s[n] = 1.0f / fmaxf(sqrtf(s), 1e-12f);
    }
    __syncthreads();

    {   // h = relu(out*scale) -> split into msh/msl
        const int row = t >> 3, c = t & 7;
        const float sc = scale_s[row];
        const float4* op = (const float4*)(outs_s + row * 136 + c * 16);
        unsigned h[8], l[8];
#pragma unroll
        for (int q = 0; q < 4; ++q) {
            float4 v = op[q];
            float a0 = fmaxf(v.x * sc, 0.f), a1 = fmaxf(v.y * sc, 0.f);
            float a2 = fmaxf(v.z * sc, 0.f), a3 = fmaxf(v.w * sc, 0.f);
            split2(a0, a1, h[2 * q], l[2 * q]);
            split2(a2, a3, h[2 * q + 1], l[2 * q + 1]);
        }
        int4 hv0 = {(int)h[0], (int)h[1], (int)h[2], (int)h[3]};
        int4 hv1 = {(int)h[4], (int)h[5], (int)h[6], (int)h[7]};
        int4 lv0 = {(int)l[0], (int)l[1], (int)l[2], (int)l[3]};
        int4 lv1 = {(int)l[4], (int)l[5], (int)l[6], (int)l[7]};
        *(int4*)((char*)msh_s + LDSWZ(row, c * 32)) = hv0;
        *(int4*)((char*)msh_s + LDSWZ(row, c * 32 + 16)) = hv1;
        *(int4*)((char*)msl_s + LDSWZ(row, c * 32)) = lv0;
        *(int4*)((char*)msl_s + LDSWZ(row, c * 32 + 16)) = lv1;
    }
    __syncthreads();

    // GEMM2: waves 0/1 -> trbf bf16 (j<64); waves 2/3 -> buf f32 self (j>=64)
    f32x4 c00 = {0.f, 0.f, 0.f, 0.f}, c01 = c00, c10 = c00, c11 = c00;
#pragma unroll
    for (int ks = 0; ks < 4; ++ks) {
        const int abo = ks * 64 + (l4 << 4);
        const short8 ah0 = *(const short8*)((const char*)msh_s + LDSWZ(l15, abo));
        const short8 ah1 = *(const short8*)((const char*)msh_s + LDSWZ(l15 + 16, abo));
        const short8 al0 = *(const short8*)((const char*)msl_s + LDSWZ(l15, abo));
        const short8 al1 = *(const short8*)((const char*)msl_s + LDSWZ(l15 + 16, abo));
        const int o0 = ((2 * wv) * 4 + ks) * 512 + lane * 8;
        const int o1 = ((2 * wv + 1) * 4 + ks) * 512 + lane * 8;
        const short8 bh0 = *(const short8*)(Wp2_h + o0);
        const short8 bl0 = *(const short8*)(Wp2_l + o0);
        const short8 bh1 = *(const short8*)(Wp2_h + o1);
        const short8 bl1 = *(const short8*)(Wp2_l + o1);
        MFMA(ah0, bh0, c00); MFMA(al0, bh0, c00); MFMA(ah0, bl0, c00);
        MFMA(ah1, bh0, c10); MFMA(al1, bh0, c10); MFMA(ah1, bl0, c10);
        MFMA(ah0, bh1, c01); MFMA(al0, bh1, c01); MFMA(ah0, bl1, c01);
        MFMA(ah1, bh1, c11); MFMA(al1, bh1, c11); MFMA(ah1, bl1, c11);
    }
    if (wv < 2) {
#pragma unroll
        for (int r2 = 0; r2 < 4; ++r2) {
            int m0 = l4 * 4 + r2;
            trbf[(gbase + m0) * 64 + wv * 32 + l15]           = rne_bf16(c00[r2]);
            trbf[(gbase + m0) * 64 + wv * 32 + 16 + l15]      = rne_bf16(c01[r2]);
            trbf[(gbase + m0 + 16) * 64 + wv * 32 + l15]      = rne_bf16(c10[r2]);
            trbf[(gbase + m0 + 16) * 64 + wv * 32 + 16 + l15] = rne_bf16(c11[r2]);
        }
    } else {
        const int cs = (wv - 2) * 32;
#pragma unroll
        for (int r2 = 0; r2 < 4; ++r2) {
            int m0 = l4 * 4 + r2;
            buf[(gbase + m0) * 128 + cs + l15]           = c00[r2];
            buf[(gbase + m0) * 128 + cs + 16 + l15]      = c01[r2];
            buf[(gbase + m0 + 16) * 128 + cs + l15]      = c10[r2];
            buf[(gbase + m0 + 16) * 128 + cs + 16 + l15] = c11[r2];
        }
    }
}

// ---- layer2: gather trbf (bf16) + bias + self (f32 in buf) + normalize ----
__global__ __launch_bounds__(256) void l2_final_k(
    const unsigned short* __restrict__ trbf, const float* __restrict__ buf,
    const int* __restrict__ esrc, const int* __restrict__ start,
    const float* __restrict__ b2l, float* __restrict__ out) {
    int n = blockIdx.x * 4 + (threadIdx.x >> 6);   // grid exact NN/4
    int c = threadIdx.x & 63;
    int s0 = start[n], s1 = start[n + 1];
    float a0 = 0.f, a1 = 0.f, a2 = 0.f, a3 = 0.f;
    int e = s0;
    for (; e + 3 < s1; e += 4) {
        a0 += __uint_as_float((unsigned)trbf[(size_t)esrc[e] * 64 + c] << 16);
        a1 += __uint_as_float((unsigned)trbf[(size_t)esrc[e + 1] * 64 + c] << 16);
        a2 += __uint_as_float((unsigned)trbf[(size_t)esrc[e + 2] * 64 + c] << 16);
        a3 += __uint_as_float((unsigned)trbf[(size_t)esrc[e + 3] * 64 + c] << 16);
    }
    for (; e < s1; ++e)
        a0 += __uint_as_float((unsigned)trbf[(size_t)esrc[e] * 64 + c] << 16);
    float inv = 1.0f / fmaxf((float)(s1 - s0), 1.0f);
    float v = (a0 + a1 + a2 + a3) * inv + b2l[c] + buf[(size_t)n * 128 + c];
    float s = v * v;
    for (int o = 1; o < 64; o <<= 1) s += __shfl_xor(s, o);
    out[(size_t)n * 64 + c] = v / fmaxf(sqrtf(s), 1e-12f);
}

extern "C" void kernel_launch(void* const* d_in, const int* in_sizes, int n_in,
                              void* d_out, int out_size, void* d_ws, size_t ws_size,
                              hipStream_t stream) {
    const float* x   = (const float*)d_in[0];
    const int*   ei  = (const int*)d_in[1];
    const float* W1l = (const float*)d_in[2];
    const float* b1l = (const float*)d_in[3];
    const float* W1r = (const float*)d_in[4];
    const float* W2l = (const float*)d_in[5];
    const float* b2l = (const float*)d_in[6];
    const float* W2r = (const float*)d_in[7];
    const int* src = ei;
    const int* dst = ei + NE;
    float* out = (float*)d_out;

    float* buf = (float*)d_ws;                                     // NN*128 f32
    unsigned short* P = (unsigned short*)(buf + (size_t)NN * 128); // 98304 u16
    int* esrc  = (int*)(P + 98304);                                // NE
    int* start = esrc + NE;                                        // NN+1
    int* cnt   = start + NN + 1;                                   // NN
    int* btot  = cnt + NN;                                         // 128
    unsigned short* trbf = (unsigned short*)(btot + 128);          // NN*64 u16
    int* rank = (int*)trbf;                                        // NE (early reuse)
    unsigned* xbf = (unsigned*)d_out;                              // NN*64 u32 (early reuse)

    hipMemsetAsync(cnt, 0, (size_t)NN * sizeof(int), stream);

    xconv_k<<<NN * 16 / 256, 256, 0, stream>>>(x, xbf);
    prep_pack_k<<<192, 256, 0, stream>>>(W1l, W1r, W2l, W2r, P);
    rank_k<<<NE / 256, 256, 0, stream>>>(dst, cnt, rank);
    scan1_k<<<NB_SCAN, 256, 0, stream>>>(cnt, start, btot);
    scan2_k<<<1, 128, 0, stream>>>(btot);
    scan3_k<<<NB_SCAN, 256, 0, stream>>>(start, btot);
    fill_k<<<NE / 256, 256, 0, stream>>>(src, dst, start, rank, esrc);
    agg1_k<<<NN / 4, 256, 0, stream>>>(xbf, esrc, start, (char*)buf);
    l12_node_k<<<NN / 32, 256, 0, stream>>>(buf, x, P, b1l, trbf);
    l2_final_k<<<NN / 4, 256, 0, stream>>>(trbf, buf, esrc, start, b2l, out);
}

// Round 8
// 393.733 us; speedup vs baseline: 11.5328x; 1.0700x over previous
//
#include <hip/hip_runtime.h>

// GraphSAGE 2-layer forward, MI355X — CSR gather (atomic-free fill) +
// MFMA split-bf16 node GEMMs + wide-request paired-edge gathers.
// N=100000, E=1600000, F=128, H=128, OUT=64.
//
// d_ws layout:
//   buf  : NN*128 f32. Per 512B row: agg1 writes [mean hi bf16 x128 | lo x128];
//          l12 overwrites bytes 0..255 with self f32 x64 (h@W2r.T).
//   P    : 98304 u16 packed B-fragment weights [W1l hi|lo][W1r hi|lo][W2 hi|lo]
//   esrc : NE int (src ids bucketed by dst)
//   start: NN+1 int,  cnt: NN int,  btot: 128 int
//   trbf : NN*64 u16 (h@W2l.T bf16) — doubles as rank[NE] int during CSR build.
// d_out doubles as xbf (NN*64 uint = bf16x2 copy of x) until l2_final writes it.

#define NN 100000
#define NE 1600000
#define SCAN_B 1024
#define NB_SCAN ((NN + SCAN_B - 1) / SCAN_B)   // 98

typedef __attribute__((ext_vector_type(8))) short short8;
typedef __attribute__((ext_vector_type(4))) float f32x4;

#define MFMA(a, b, c) c = __builtin_amdgcn_mfma_f32_16x16x32_bf16(a, b, c, 0, 0, 0)
#define LDSWZ(row, bo) (((row) * 256) + ((bo) ^ (((row) & 7) << 4)))

__device__ __forceinline__ float bflo(unsigned u) { return __uint_as_float(u << 16); }
__device__ __forceinline__ float bfhi(unsigned u) { return __uint_as_float(u & 0xFFFF0000u); }

__device__ __forceinline__ unsigned short rne_bf16(float f) {
    unsigned u = __float_as_uint(f);
    unsigned r = u + 0x7FFFu + ((u >> 16) & 1u);
    return (unsigned short)(r >> 16);
}

// split pair (a,b) -> hi (truncate, a in low16) + lo (RNE of residual)
__device__ __forceinline__ void split2(float a, float b, unsigned& hi, unsigned& lo) {
    unsigned ua = __float_as_uint(a), ub = __float_as_uint(b);
    hi = (ub & 0xFFFF0000u) | (ua >> 16);
    float la = a - __uint_as_float(ua & 0xFFFF0000u);
    float lb = b - __uint_as_float(ub & 0xFFFF0000u);
    lo = ((unsigned)rne_bf16(lb) << 16) | rne_bf16(la);
}

// ---- x -> bf16x2 copy (for agg1 gather), 8 elems/thread ----
__global__ void xconv_k(const float* __restrict__ x, unsigned* __restrict__ xbf) {
    int t = blockIdx.x * 256 + threadIdx.x;   // grid exact NN*16/256
    const float4* p = (const float4*)(x + (size_t)t * 8);
    float4 v0 = p[0], v1 = p[1];
    uint4 r;
    r.x = ((unsigned)rne_bf16(v0.y) << 16) | rne_bf16(v0.x);
    r.y = ((unsigned)rne_bf16(v0.w) << 16) | rne_bf16(v0.z);
    r.z = ((unsigned)rne_bf16(v1.y) << 16) | rne_bf16(v1.x);
    r.w = ((unsigned)rne_bf16(v1.w) << 16) | rne_bf16(v1.z);
    *(uint4*)(xbf + (size_t)t * 4) = r;
}

// ---- weight pack: B-fragment layout, split hi/lo ----
__global__ void prep_pack_k(const float* __restrict__ W1l, const float* __restrict__ W1r,
                            const float* __restrict__ W2l, const float* __restrict__ W2r,
                            unsigned short* __restrict__ P) {
    int p = blockIdx.x * 256 + threadIdx.x;   // 0..49151
    int mat = p / 16384;
    int q = p - mat * 16384;
    int i = q & 7, l = (q >> 3) & 63, f = q >> 9;
    int jt = f >> 2, ks = f & 3;
    int j = jt * 16 + (l & 15);
    int k = ks * 32 + (l >> 4) * 8 + i;
    float w;
    if (mat == 0)      w = W1l[j * 128 + k];
    else if (mat == 1) w = W1r[j * 128 + k];
    else               w = (j < 64) ? W2l[j * 128 + k] : W2r[(j - 64) * 128 + k];
    unsigned short hi = rne_bf16(w);
    float whi = __uint_as_float(((unsigned)hi) << 16);
    unsigned short lo = rne_bf16(w - whi);
    P[mat * 32768 + q] = hi;
    P[mat * 32768 + 16384 + q] = lo;
}

// ---- degree histogram + per-edge rank (atomic return value) ----
__global__ void rank_k(const int* __restrict__ dst, int* __restrict__ cnt,
                       int* __restrict__ rank) {
    int e = blockIdx.x * 256 + threadIdx.x;
    rank[e] = atomicAdd(&cnt[dst[e]], 1);
}

// ---- exclusive scan (3 passes) ----
__global__ void scan1_k(const int* __restrict__ cnt, int* __restrict__ start,
                        int* __restrict__ btot) {
    __shared__ int sd[256];
    int b = blockIdx.x, t = threadIdx.x;
    int base = b * SCAN_B + t * 4;
    int v0 = (base + 0 < NN) ? cnt[base + 0] : 0;
    int v1 = (base + 1 < NN) ? cnt[base + 1] : 0;
    int v2 = (base + 2 < NN) ? cnt[base + 2] : 0;
    int v3 = (base + 3 < NN) ? cnt[base + 3] : 0;
    int sum = v0 + v1 + v2 + v3;
    sd[t] = sum;
    __syncthreads();
    for (int o = 1; o < 256; o <<= 1) {
        int x = (t >= o) ? sd[t - o] : 0;
        __syncthreads();
        sd[t] += x;
        __syncthreads();
    }
    int run = sd[t] - sum;
    if (base + 0 < NN) start[base + 0] = run; run += v0;
    if (base + 1 < NN) start[base + 1] = run; run += v1;
    if (base + 2 < NN) start[base + 2] = run; run += v2;
    if (base + 3 < NN) start[base + 3] = run;
    if (t == 255) btot[b] = sd[255];
}

__global__ void scan2_k(int* __restrict__ btot) {
    __shared__ int sd[128];
    int t = threadIdx.x;
    int v = (t < NB_SCAN) ? btot[t] : 0;
    sd[t] = v;
    __syncthreads();
    for (int o = 1; o < 128; o <<= 1) {
        int x = (t >= o) ? sd[t - o] : 0;
        __syncthreads();
        sd[t] += x;
        __syncthreads();
    }
    if (t < NB_SCAN) btot[t] = sd[t] - v;
}

__global__ void scan3_k(int* __restrict__ start, const int* __restrict__ btot) {
    int b = blockIdx.x;
    int off = btot[b];
    int base = b * SCAN_B + threadIdx.x;
#pragma unroll
    for (int i = 0; i < 4; ++i) {
        int idx = base + i * 256;
        if (idx < NN) start[idx] += off;
    }
    if (b == 0 && threadIdx.x == 0) start[NN] = NE;
}

// ---- bucket fill (no atomics) ----
__global__ void fill_k(const int* __restrict__ src, const int* __restrict__ dst,
                       const int* __restrict__ start, const int* __restrict__ rank,
                       int* __restrict__ esrc) {
    int e = blockIdx.x * 256 + threadIdx.x;
    esrc[start[dst[e]] + rank[e]] = src[e];
}

// ---- layer1 gather (bf16 x): mean per node -> split hi/lo row in buf.
//      1 wave/node; 2 edges per VMEM instruction (32 lanes x uint2 = 256B/edge). ----
__global__ __launch_bounds__(256) void agg1_k(const unsigned* __restrict__ xbf,
                                              const int* __restrict__ esrc,
                                              const int* __restrict__ start,
                                              char* __restrict__ buf) {
    int n = blockIdx.x * 4 + (threadIdx.x >> 6);   // grid exact NN/4
    int l = threadIdx.x & 63;
    int slot = l >> 5, q = l & 31;                 // lane covers channels 4q..4q+3
    const uint2* x2 = (const uint2*)xbf;           // row = 32 uint2
    int s0 = start[n], s1 = start[n + 1];
    float a0 = 0.f, a1 = 0.f, a2 = 0.f, a3 = 0.f;
    float b0 = 0.f, b1 = 0.f, b2 = 0.f, b3 = 0.f;
    int e = s0;
    for (; e + 3 < s1; e += 4) {                   // 4 edges: 2 wide requests
        uint2 va = x2[(size_t)esrc[e + slot] * 32 + q];
        uint2 vb = x2[(size_t)esrc[e + 2 + slot] * 32 + q];
        a0 += bflo(va.x); a1 += bfhi(va.x); a2 += bflo(va.y); a3 += bfhi(va.y);
        b0 += bflo(vb.x); b1 += bfhi(vb.x); b2 += bflo(vb.y); b3 += bfhi(vb.y);
    }
    for (; e + 1 < s1; e += 2) {
        uint2 va = x2[(size_t)esrc[e + slot] * 32 + q];
        a0 += bflo(va.x); a1 += bfhi(va.x); a2 += bflo(va.y); a3 += bfhi(va.y);
    }
    if (e < s1 && slot == 0) {                     // tail edge: half-wave
        uint2 va = x2[(size_t)esrc[e] * 32 + q];
        a0 += bflo(va.x); a1 += bfhi(va.x); a2 += bflo(va.y); a3 += bfhi(va.y);
    }
    a0 += b0; a1 += b1; a2 += b2; a3 += b3;
    a0 += __shfl_xor(a0, 32); a1 += __shfl_xor(a1, 32);
    a2 += __shfl_xor(a2, 32); a3 += __shfl_xor(a3, 32);
    float inv = 1.0f / fmaxf((float)(s1 - s0), 1.0f);
    unsigned h0, l0, h1, l1;
    split2(a0 * inv, a1 * inv, h0, l0);
    split2(a2 * inv, a3 * inv, h1, l1);
    char* row = buf + (size_t)n * 512;
    uint2 w;
    if (slot == 0) { w.x = h0; w.y = h1; ((uint2*)row)[q] = w; }
    else           { w.x = l0; w.y = l1; ((uint2*)(row + 256))[q] = w; }
}

// ---- fused node kernel (MFMA): h = relu(norm(mean@W1l.T + b1l + x@W1r.T));
//      trbf <- bf16(h@W2l.T); buf row bytes 0..255 <- f32(h@W2r.T). ----
__global__ __launch_bounds__(256, 3) void l12_node_k(
    float* __restrict__ buf, const float* __restrict__ x,
    const unsigned short* __restrict__ P, const float* __restrict__ b1l,
    unsigned short* __restrict__ trbf) {
    __shared__ unsigned short msh_s[32 * 128];
    __shared__ unsigned short msl_s[32 * 128];
    __shared__ unsigned short xsh_s[32 * 128];
    __shared__ unsigned short xsl_s[32 * 128];
    __shared__ float outs_s[32 * 136];
    __shared__ float scale_s[32];

    const int t = threadIdx.x;
    const size_t gbase = (size_t)blockIdx.x * 32;

    {   // stage: mean copy + x split-convert
        const int row = t >> 3, c = t & 7;
        const char* brow = (const char*)buf + (gbase + row) * 512;
        int4 mh0 = *(const int4*)(brow + c * 32);
        int4 mh1 = *(const int4*)(brow + c * 32 + 16);
        int4 ml0 = *(const int4*)(brow + 256 + c * 32);
        int4 ml1 = *(const int4*)(brow + 256 + c * 32 + 16);
        *(int4*)((char*)msh_s + LDSWZ(row, c * 32)) = mh0;
        *(int4*)((char*)msh_s + LDSWZ(row, c * 32 + 16)) = mh1;
        *(int4*)((char*)msl_s + LDSWZ(row, c * 32)) = ml0;
        *(int4*)((char*)msl_s + LDSWZ(row, c * 32 + 16)) = ml1;

        const float* xrow = x + (gbase + row) * 128 + c * 16;
        unsigned h[8], l[8];
#pragma unroll
        for (int qq = 0; qq < 4; ++qq) {
            float4 v = *(const float4*)(xrow + 4 * qq);
            split2(v.x, v.y, h[2 * qq], l[2 * qq]);
            split2(v.z, v.w, h[2 * qq + 1], l[2 * qq + 1]);
        }
        int4 hv0 = {(int)h[0], (int)h[1], (int)h[2], (int)h[3]};
        int4 hv1 = {(int)h[4], (int)h[5], (int)h[6], (int)h[7]};
        int4 lv0 = {(int)l[0], (int)l[1], (int)l[2], (int)l[3]};
        int4 lv1 = {(int)l[4], (int)l[5], (int)l[6], (int)l[7]};
        *(int4*)((char*)xsh_s + LDSWZ(row, c * 32)) = hv0;
        *(int4*)((char*)xsh_s + LDSWZ(row, c * 32 + 16)) = hv1;
        *(int4*)((char*)xsl_s + LDSWZ(row, c * 32)) = lv0;
        *(int4*)((char*)xsl_s + LDSWZ(row, c * 32 + 16)) = lv1;
    }
    __syncthreads();

    const int lane = t & 63;
    const int wv = t >> 6;
    const int l15 = lane & 15;
    const int l4 = lane >> 4;
    const unsigned short* Wp1l_h = P;
    const unsigned short* Wp1l_l = P + 16384;
    const unsigned short* Wp1r_h = P + 32768;
    const unsigned short* Wp1r_l = P + 49152;
    const unsigned short* Wp2_h  = P + 65536;
    const unsigned short* Wp2_l  = P + 81920;

    // GEMM1
    f32x4 acc00 = {0.f, 0.f, 0.f, 0.f}, acc01 = acc00, acc10 = acc00, acc11 = acc00;
#pragma unroll
    for (int ks = 0; ks < 4; ++ks) {
        const int abo = ks * 64 + (l4 << 4);
        const short8 amh0 = *(const short8*)((const char*)msh_s + LDSWZ(l15, abo));
        const short8 amh1 = *(const short8*)((const char*)msh_s + LDSWZ(l15 + 16, abo));
        const short8 aml0 = *(const short8*)((const char*)msl_s + LDSWZ(l15, abo));
        const short8 aml1 = *(const short8*)((const char*)msl_s + LDSWZ(l15 + 16, abo));
        const short8 axh0 = *(const short8*)((const char*)xsh_s + LDSWZ(l15, abo));
        const short8 axh1 = *(const short8*)((const char*)xsh_s + LDSWZ(l15 + 16, abo));
        const short8 axl0 = *(const short8*)((const char*)xsl_s + LDSWZ(l15, abo));
        const short8 axl1 = *(const short8*)((const char*)xsl_s + LDSWZ(l15 + 16, abo));
        const int o0 = ((2 * wv) * 4 + ks) * 512 + lane * 8;
        const int o1 = ((2 * wv + 1) * 4 + ks) * 512 + lane * 8;
        const short8 blh0 = *(const short8*)(Wp1l_h + o0);
        const short8 bll0 = *(const short8*)(Wp1l_l + o0);
        const short8 brh0 = *(const short8*)(Wp1r_h + o0);
        const short8 brl0 = *(const short8*)(Wp1r_l + o0);
        const short8 blh1 = *(const short8*)(Wp1l_h + o1);
        const short8 bll1 = *(const short8*)(Wp1l_l + o1);
        const short8 brh1 = *(const short8*)(Wp1r_h + o1);
        const short8 brl1 = *(const short8*)(Wp1r_l + o1);
        MFMA(amh0, blh0, acc00); MFMA(aml0, blh0, acc00); MFMA(amh0, bll0, acc00);
        MFMA(axh0, brh0, acc00); MFMA(axl0, brh0, acc00); MFMA(axh0, brl0, acc00);
        MFMA(amh1, blh0, acc10); MFMA(aml1, blh0, acc10); MFMA(amh1, bll0, acc10);
        MFMA(axh1, brh0, acc10); MFMA(axl1, brh0, acc10); MFMA(axh1, brl0, acc10);
        MFMA(amh0, blh1, acc01); MFMA(aml0, blh1, acc01); MFMA(amh0, bll1, acc01);
        MFMA(axh0, brh1, acc01); MFMA(axl0, brh1, acc01); MFMA(axh0, brl1, acc01);
        MFMA(amh1, blh1, acc11); MFMA(aml1, blh1, acc11); MFMA(amh1, bll1, acc11);
        MFMA(axh1, brh1, acc11); MFMA(axl1, brh1, acc11); MFMA(axh1, brl1, acc11);
    }
    {
        float bi0 = b1l[wv * 32 + l15];
        float bi1 = b1l[wv * 32 + 16 + l15];
#pragma unroll
        for (int r2 = 0; r2 < 4; ++r2) {
            int m0 = l4 * 4 + r2;
            outs_s[m0 * 136 + wv * 32 + l15]             = acc00[r2] + bi0;
            outs_s[m0 * 136 + wv * 32 + 16 + l15]        = acc01[r2] + bi1;
            outs_s[(m0 + 16) * 136 + wv * 32 + l15]      = acc10[r2] + bi0;
            outs_s[(m0 + 16) * 136 + wv * 32 + 16 + l15] = acc11[r2] + bi1;
        }
    }
    __syncthreads();

    {   // row norms
        const int n = t >> 3, lo16 = (t & 7) * 16;
        const float4* op = (const float4*)(outs_s + n * 136 + lo16);
        float s = 0.f;
#pragma unroll
        for (int qq = 0; qq < 4; ++qq) {
            float4 v = op[qq];
            s += v.x * v.x + v.y * v.y + v.z * v.z + v.w * v.w;
        }
        s += __shfl_xor(s, 1);
        s += __shfl_xor(s, 2);
        s += __shfl_xor(s, 4);
        if ((t & 7) == 0) scale_s[n] = 1.0f / fmaxf(sqrtf(s), 1e-12f);
    }
    __syncthreads();

    {   // h = relu(out*scale) -> split into msh/msl
        const int row = t >> 3, c = t & 7;
        const float sc = scale_s[row];
        const float4* op = (const float4*)(outs_s + row * 136 + c * 16);
        unsigned h[8], l[8];
#pragma unroll
        for (int qq = 0; qq < 4; ++qq) {
            float4 v = op[qq];
            float a0 = fmaxf(v.x * sc, 0.f), a1 = fmaxf(v.y * sc, 0.f);
            float a2 = fmaxf(v.z * sc, 0.f), a3 = fmaxf(v.w * sc, 0.f);
            split2(a0, a1, h[2 * qq], l[2 * qq]);
            split2(a2, a3, h[2 * qq + 1], l[2 * qq + 1]);
        }
        int4 hv0 = {(int)h[0], (int)h[1], (int)h[2], (int)h[3]};
        int4 hv1 = {(int)h[4], (int)h[5], (int)h[6], (int)h[7]};
        int4 lv0 = {(int)l[0], (int)l[1], (int)l[2], (int)l[3]};
        int4 lv1 = {(int)l[4], (int)l[5], (int)l[6], (int)l[7]};
        *(int4*)((char*)msh_s + LDSWZ(row, c * 32)) = hv0;
        *(int4*)((char*)msh_s + LDSWZ(row, c * 32 + 16)) = hv1;
        *(int4*)((char*)msl_s + LDSWZ(row, c * 32)) = lv0;
        *(int4*)((char*)msl_s + LDSWZ(row, c * 32 + 16)) = lv1;
    }
    __syncthreads();

    // GEMM2: waves 0/1 -> trbf bf16 (j<64); waves 2/3 -> buf f32 self (j>=64)
    f32x4 c00 = {0.f, 0.f, 0.f, 0.f}, c01 = c00, c10 = c00, c11 = c00;
#pragma unroll
    for (int ks = 0; ks < 4; ++ks) {
        const int abo = ks * 64 + (l4 << 4);
        const short8 ah0 = *(const short8*)((const char*)msh_s + LDSWZ(l15, abo));
        const short8 ah1 = *(const short8*)((const char*)msh_s + LDSWZ(l15 + 16, abo));
        const short8 al0 = *(const short8*)((const char*)msl_s + LDSWZ(l15, abo));
        const short8 al1 = *(const short8*)((const char*)msl_s + LDSWZ(l15 + 16, abo));
        const int o0 = ((2 * wv) * 4 + ks) * 512 + lane * 8;
        const int o1 = ((2 * wv + 1) * 4 + ks) * 512 + lane * 8;
        const short8 bh0 = *(const short8*)(Wp2_h + o0);
        const short8 bl0 = *(const short8*)(Wp2_l + o0);
        const short8 bh1 = *(const short8*)(Wp2_h + o1);
        const short8 bl1 = *(const short8*)(Wp2_l + o1);
        MFMA(ah0, bh0, c00); MFMA(al0, bh0, c00); MFMA(ah0, bl0, c00);
        MFMA(ah1, bh0, c10); MFMA(al1, bh0, c10); MFMA(ah1, bl0, c10);
        MFMA(ah0, bh1, c01); MFMA(al0, bh1, c01); MFMA(ah0, bl1, c01);
        MFMA(ah1, bh1, c11); MFMA(al1, bh1, c11); MFMA(ah1, bl1, c11);
    }
    if (wv < 2) {
#pragma unroll
        for (int r2 = 0; r2 < 4; ++r2) {
            int m0 = l4 * 4 + r2;
            trbf[(gbase + m0) * 64 + wv * 32 + l15]           = rne_bf16(c00[r2]);
            trbf[(gbase + m0) * 64 + wv * 32 + 16 + l15]      = rne_bf16(c01[r2]);
            trbf[(gbase + m0 + 16) * 64 + wv * 32 + l15]      = rne_bf16(c10[r2]);
            trbf[(gbase + m0 + 16) * 64 + wv * 32 + 16 + l15] = rne_bf16(c11[r2]);
        }
    } else {
        const int cs = (wv - 2) * 32;
#pragma unroll
        for (int r2 = 0; r2 < 4; ++r2) {
            int m0 = l4 * 4 + r2;
            buf[(gbase + m0) * 128 + cs + l15]           = c00[r2];
            buf[(gbase + m0) * 128 + cs + 16 + l15]      = c01[r2];
            buf[(gbase + m0 + 16) * 128 + cs + l15]      = c10[r2];
            buf[(gbase + m0 + 16) * 128 + cs + 16 + l15] = c11[r2];
        }
    }
}

// ---- layer2: gather trbf (bf16) + bias + self + normalize.
//      1 wave/node; 4 edges per VMEM instruction (16 lanes x uint2 = 128B/edge). ----
__global__ __launch_bounds__(256) void l2_final_k(
    const unsigned short* __restrict__ trbf, const float* __restrict__ buf,
    const int* __restrict__ esrc, const int* __restrict__ start,
    const float* __restrict__ b2l, float* __restrict__ out) {
    int n = blockIdx.x * 4 + (threadIdx.x >> 6);   // grid exact NN/4
    int l = threadIdx.x & 63;
    int slot = l >> 4, q = l & 15;                 // lane covers channels 4q..4q+3
    const uint2* t2 = (const uint2*)trbf;          // row = 16 uint2
    int s0 = start[n], s1 = start[n + 1];
    float a0 = 0.f, a1 = 0.f, a2 = 0.f, a3 = 0.f;
    float b0 = 0.f, b1 = 0.f, b2 = 0.f, b3 = 0.f;
    int e = s0;
    for (; e + 7 < s1; e += 8) {                   // 8 edges: 2 wide requests
        uint2 va = t2[(size_t)esrc[e + slot] * 16 + q];
        uint2 vb = t2[(size_t)esrc[e + 4 + slot] * 16 + q];
        a0 += bflo(va.x); a1 += bfhi(va.x); a2 += bflo(va.y); a3 += bfhi(va.y);
        b0 += bflo(vb.x); b1 += bfhi(vb.x); b2 += bflo(vb.y); b3 += bfhi(vb.y);
    }
    for (; e + 3 < s1; e += 4) {
        uint2 va = t2[(size_t)esrc[e + slot] * 16 + q];
        a0 += bflo(va.x); a1 += bfhi(va.x); a2 += bflo(va.y); a3 += bfhi(va.y);
    }
    for (; e < s1; ++e) {
        if (slot == 0) {
            uint2 va = t2[(size_t)esrc[e] * 16 + q];
            a0 += bflo(va.x); a1 += bfhi(va.x); a2 += bflo(va.y); a3 += bfhi(va.y);
        }
    }
    a0 += b0; a1 += b1; a2 += b2; a3 += b3;
    a0 += __shfl_xor(a0, 16); a0 += __shfl_xor(a0, 32);
    a1 += __shfl_xor(a1, 16); a1 += __shfl_xor(a1, 32);
    a2 += __shfl_xor(a2, 16); a2 += __shfl_xor(a2, 32);
    a3 += __shfl_xor(a3, 16); a3 += __shfl_xor(a3, 32);
    float inv = 1.0f / fmaxf((float)(s1 - s0), 1.0f);
    float4 bia = ((const float4*)b2l)[q];
    float4 self = *(const float4*)(buf + (size_t)n * 128 + 4 * q);
    float v0 = a0 * inv + bia.x + self.x;
    float v1 = a1 * inv + bia.y + self.y;
    float v2 = a2 * inv + bia.z + self.z;
    float v3 = a3 * inv + bia.w + self.w;
    float s = v0 * v0 + v1 * v1 + v2 * v2 + v3 * v3;
    s += __shfl_xor(s, 1);
    s += __shfl_xor(s, 2);
    s += __shfl_xor(s, 4);
    s += __shfl_xor(s, 8);
    float sc = 1.0f / fmaxf(sqrtf(s), 1e-12f);
    if (slot == 0) {
        float4 r = {v0 * sc, v1 * sc, v2 * sc, v3 * sc};
        *(float4*)(out + (size_t)n * 64 + 4 * q) = r;
    }
}

extern "C" void kernel_launch(void* const* d_in, const int* in_sizes, int n_in,
                              void* d_out, int out_size, void* d_ws, size_t ws_size,
                              hipStream_t stream) {
    const float* x   = (const float*)d_in[0];
    const int*   ei  = (const int*)d_in[1];
    const float* W1l = (const float*)d_in[2];
    const float* b1l = (const float*)d_in[3];
    const float* W1r = (const float*)d_in[4];
    const float* W2l = (const float*)d_in[5];
    const float* b2l = (const float*)d_in[6];
    const float* W2r = (const float*)d_in[7];
    const int* src = ei;
    const int* dst = ei + NE;
    float* out = (float*)d_out;

    float* buf = (float*)d_ws;                                     // NN*128 f32
    unsigned short* P = (unsigned short*)(buf + (size_t)NN * 128); // 98304 u16
    int* esrc  = (int*)(P + 98304);                                // NE
    int* start = esrc + NE;                                        // NN+1
    int* cnt   = start + NN + 1;                                   // NN
    int* btot  = cnt + NN;                                         // 128
    unsigned short* trbf = (unsigned short*)(btot + 128);          // NN*64 u16
    int* rank = (int*)trbf;                                        // NE (early reuse)
    unsigned* xbf = (unsigned*)d_out;                              // NN*64 u32 (early reuse)

    hipMemsetAsync(cnt, 0, (size_t)NN * sizeof(int), stream);

    xconv_k<<<NN * 16 / 256, 256, 0, stream>>>(x, xbf);
    prep_pack_k<<<192, 256, 0, stream>>>(W1l, W1r, W2l, W2r, P);
    rank_k<<<NE / 256, 256, 0, stream>>>(dst, cnt, rank);
    scan1_k<<<NB_SCAN, 256, 0, stream>>>(cnt, start, btot);
    scan2_k<<<1, 128, 0, stream>>>(btot);
    scan3_k<<<NB_SCAN, 256, 0, stream>>>(start, btot);
    fill_k<<<NE / 256, 256, 0, stream>>>(src, dst, start, rank, esrc);
    agg1_k<<<NN / 4, 256, 0, stream>>>(xbf, esrc, start, (char*)buf);
    l12_node_k<<<NN / 32, 256, 0, stream>>>(buf, x, P, b1l, trbf);
    l2_final_k<<<NN / 4, 256, 0, stream>>>(trbf, buf, esrc, start, b2l, out);
}